// Round 1
// baseline (1000.579 us; speedup 1.0000x reference)
//
#include <hip/hip_runtime.h>
#include <math.h>

#define T 2048
#define DM 640
#define NH 14
#define NKV 2
#define HPK 7
#define HD 64
#define QDIM 896
#define QKV_DIM 1152

constexpr float QK_SCALE = 0.35355339059327373f; // 64^-0.25
constexpr float LN2F = 0.6931471805599453f;
constexpr float EPSF = 1e-5f;

// ---------------------------------------------------------------- RMSNorm rstd
__global__ __launch_bounds__(256) void rstd_partial_kernel(
    const float* __restrict__ x, float* __restrict__ rpart)
{
    const int t = blockIdx.x * 256 + threadIdx.x;
    const int cb = blockIdx.y; // 0..9, 64 channels each
    float ss = 0.f;
    #pragma unroll 8
    for (int i = 0; i < 64; ++i) {
        float v = x[(cb * 64 + i) * T + t];
        ss = fmaf(v, v, ss);
    }
    rpart[cb * T + t] = ss;
}

__global__ __launch_bounds__(256) void rstd_final_kernel(
    const float* __restrict__ rpart, float* __restrict__ rstd)
{
    const int t = blockIdx.x * 256 + threadIdx.x;
    float ss = 0.f;
    #pragma unroll
    for (int j = 0; j < 10; ++j) ss += rpart[j * T + t];
    rstd[t] = rsqrtf(ss * (1.0f / DM) + EPSF);
}

// ------------------------------------------------- QKV GEMM + bias + RoPE + scale
// out[t][o] = sum_c x[c][t]*norm_w[c]*rstd[t] * qkv_w[o][c]  (+bias, rope, scale)
__global__ __launch_bounds__(256) void qkv_gemm_kernel(
    const float* __restrict__ x, const float* __restrict__ norm_w,
    const float* __restrict__ rstd, const float* __restrict__ qkv_w,
    const float* __restrict__ qkv_b, const float* __restrict__ rope_cos,
    const float* __restrict__ rope_sin, float* __restrict__ Qb,
    float* __restrict__ Kb, float* __restrict__ Vb)
{
    const int tid = threadIdx.x;
    const int tx = tid & 15, ty = tid >> 4;
    const int t0 = blockIdx.x * 64;
    const int o0 = blockIdx.y * 64;

    __shared__ float As[16][64];  // [c-local][t-local]
    __shared__ float Bs[16][68];  // [c-local][o-local], padded

    float acc[4][4] = {{0.f}};

    const int a_kc = tid >> 4;          // c-local 0..15
    const int a_tt = (tid & 15) * 4;    // t-local 0..60
    const int b_row = tid >> 2;         // o-local 0..63
    const int b_off = (tid & 3) * 4;    // c-local 0,4,8,12

    const float4 rs = *(const float4*)&rstd[t0 + a_tt];

    for (int c0 = 0; c0 < DM; c0 += 16) {
        float4 av = *(const float4*)&x[(c0 + a_kc) * T + t0 + a_tt];
        const float nw = norm_w[c0 + a_kc];
        av.x *= nw * rs.x; av.y *= nw * rs.y; av.z *= nw * rs.z; av.w *= nw * rs.w;
        const float4 bv = *(const float4*)&qkv_w[(o0 + b_row) * DM + c0 + b_off];
        __syncthreads();
        *(float4*)&As[a_kc][a_tt] = av;
        Bs[b_off + 0][b_row] = bv.x;
        Bs[b_off + 1][b_row] = bv.y;
        Bs[b_off + 2][b_row] = bv.z;
        Bs[b_off + 3][b_row] = bv.w;
        __syncthreads();
        #pragma unroll
        for (int kk = 0; kk < 16; ++kk) {
            const float4 a = *(const float4*)&As[kk][ty * 4];
            const float4 b = *(const float4*)&Bs[kk][tx * 4];
            acc[0][0] = fmaf(a.x, b.x, acc[0][0]);
            acc[0][1] = fmaf(a.x, b.y, acc[0][1]);
            acc[0][2] = fmaf(a.x, b.z, acc[0][2]);
            acc[0][3] = fmaf(a.x, b.w, acc[0][3]);
            acc[1][0] = fmaf(a.y, b.x, acc[1][0]);
            acc[1][1] = fmaf(a.y, b.y, acc[1][1]);
            acc[1][2] = fmaf(a.y, b.z, acc[1][2]);
            acc[1][3] = fmaf(a.y, b.w, acc[1][3]);
            acc[2][0] = fmaf(a.z, b.x, acc[2][0]);
            acc[2][1] = fmaf(a.z, b.y, acc[2][1]);
            acc[2][2] = fmaf(a.z, b.z, acc[2][2]);
            acc[2][3] = fmaf(a.z, b.w, acc[2][3]);
            acc[3][0] = fmaf(a.w, b.x, acc[3][0]);
            acc[3][1] = fmaf(a.w, b.y, acc[3][1]);
            acc[3][2] = fmaf(a.w, b.z, acc[3][2]);
            acc[3][3] = fmaf(a.w, b.w, acc[3][3]);
        }
    }

    const int dloc = tx * 4;                 // d within head (o0 is head-aligned)
    const int t_base = t0 + ty * 4;
    const float4 bias = *(const float4*)&qkv_b[o0 + dloc];
    const int by = blockIdx.y;

    if (by < 14) { // Q heads, rope + scale
        const int h = by;
        #pragma unroll
        for (int i = 0; i < 4; ++i) {
            const int t = t_base + i;
            const float e0 = acc[i][0] + bias.x, d1 = acc[i][1] + bias.y;
            const float e2 = acc[i][2] + bias.z, d3 = acc[i][3] + bias.w;
            const float c0v = rope_cos[t * 32 + (dloc >> 1)];
            const float s0v = rope_sin[t * 32 + (dloc >> 1)];
            const float c1v = rope_cos[t * 32 + (dloc >> 1) + 1];
            const float s1v = rope_sin[t * 32 + (dloc >> 1) + 1];
            float4 qv;
            qv.x = (e0 * c0v - d1 * s0v) * QK_SCALE;
            qv.y = (d1 * c0v + e0 * s0v) * QK_SCALE;
            qv.z = (e2 * c1v - d3 * s1v) * QK_SCALE;
            qv.w = (d3 * c1v + e2 * s1v) * QK_SCALE;
            *(float4*)&Qb[(h * T + t) * HD + dloc] = qv;
        }
    } else if (by < 16) { // K heads, rope + scale
        const int h = by - 14;
        #pragma unroll
        for (int i = 0; i < 4; ++i) {
            const int t = t_base + i;
            const float e0 = acc[i][0] + bias.x, d1 = acc[i][1] + bias.y;
            const float e2 = acc[i][2] + bias.z, d3 = acc[i][3] + bias.w;
            const float c0v = rope_cos[t * 32 + (dloc >> 1)];
            const float s0v = rope_sin[t * 32 + (dloc >> 1)];
            const float c1v = rope_cos[t * 32 + (dloc >> 1) + 1];
            const float s1v = rope_sin[t * 32 + (dloc >> 1) + 1];
            float4 kv;
            kv.x = (e0 * c0v - d1 * s0v) * QK_SCALE;
            kv.y = (d1 * c0v + e0 * s0v) * QK_SCALE;
            kv.z = (e2 * c1v - d3 * s1v) * QK_SCALE;
            kv.w = (d3 * c1v + e2 * s1v) * QK_SCALE;
            *(float4*)&Kb[(h * T + t) * HD + dloc] = kv;
        }
    } else { // V heads, plain
        const int h = by - 16;
        #pragma unroll
        for (int i = 0; i < 4; ++i) {
            const int t = t_base + i;
            float4 vv;
            vv.x = acc[i][0] + bias.x;
            vv.y = acc[i][1] + bias.y;
            vv.z = acc[i][2] + bias.z;
            vv.w = acc[i][3] + bias.w;
            *(float4*)&Vb[(h * T + t) * HD + dloc] = vv;
        }
    }
}

// --------------------------------------------- attention: split-K partial pass
// block = (qt, h, kc); 64 threads, one q-row each; k range = [kc*512, (kc+1)*512)
__global__ __launch_bounds__(64) void attn_partial_kernel(
    const float* __restrict__ Qb, const float* __restrict__ Kb,
    const float* __restrict__ Vb, const float* __restrict__ sinks,
    float* __restrict__ Opart, float* __restrict__ Mpart, float* __restrict__ Lpart)
{
    const int qt = blockIdx.x;
    const int h  = blockIdx.y;
    const int kc = blockIdx.z;
    if (kc * 8 > qt) return;

    const int lane = threadIdx.x;
    const int r = qt * 64 + lane;
    const int kvh = h / HPK;

    __shared__ float Ks[64][68];
    __shared__ float Vs[64][68];

    float q[64], oacc[64];
    #pragma unroll
    for (int d = 0; d < 64; d += 4) {
        *(float4*)&q[d] = *(const float4*)&Qb[(h * T + r) * HD + d];
        oacc[d] = 0.f; oacc[d+1] = 0.f; oacc[d+2] = 0.f; oacc[d+3] = 0.f;
    }
    float m, l;
    if (kc == 0) { m = sinks[h] * LN2F; l = 1.0f; }
    else         { m = -3e38f;          l = 0.0f; }

    const int kt_end = min(kc * 8 + 8, qt + 1);
    for (int kt = kc * 8; kt < kt_end; ++kt) {
        __syncthreads();
        #pragma unroll
        for (int d = 0; d < 64; d += 4) {
            *(float4*)&Ks[lane][d] = *(const float4*)&Kb[(kvh * T + kt * 64 + lane) * HD + d];
            *(float4*)&Vs[lane][d] = *(const float4*)&Vb[(kvh * T + kt * 64 + lane) * HD + d];
        }
        __syncthreads();
        const int kbase = kt * 64;
        for (int k = 0; k < 64; ++k) {
            float s0 = 0.f, s1 = 0.f, s2 = 0.f, s3 = 0.f;
            #pragma unroll
            for (int d = 0; d < 64; d += 4) {
                const float4 kv4 = *(const float4*)&Ks[k][d];
                s0 = fmaf(q[d],     kv4.x, s0);
                s1 = fmaf(q[d + 1], kv4.y, s1);
                s2 = fmaf(q[d + 2], kv4.z, s2);
                s3 = fmaf(q[d + 3], kv4.w, s3);
            }
            float s = (s0 + s1) + (s2 + s3);
            s += (kbase + k > r) ? -1e9f : 0.f;   // causal mask, as in reference
            const float mnew = fmaxf(m, s);
            if (mnew > m) {
                const float corr = __expf(m - mnew);
                l *= corr;
                #pragma unroll
                for (int d = 0; d < 64; ++d) oacc[d] *= corr;
                m = mnew;
            }
            const float p = __expf(s - mnew);
            l += p;
            #pragma unroll
            for (int d = 0; d < 64; ++d) oacc[d] = fmaf(p, Vs[k][d], oacc[d]);
        }
    }

    const int pb = (h * 4 + kc) * 64;
    #pragma unroll
    for (int d = 0; d < 64; ++d)
        Opart[(pb + d) * T + r] = oacc[d];
    Mpart[(h * 4 + kc) * T + r] = m;
    Lpart[(h * 4 + kc) * T + r] = l;
}

// --------------------------------------------- attention: combine partials
__global__ __launch_bounds__(256) void attn_combine_kernel(
    const float* __restrict__ Opart, const float* __restrict__ Mpart,
    const float* __restrict__ Lpart, float* __restrict__ AOT)
{
    const int idx = blockIdx.x * 256 + threadIdx.x; // [0, NH*T)
    const int h = idx >> 11;
    const int r = idx & (T - 1);
    const int nch = (r >> 9) + 1; // chunks of 512 keys

    float mv0 = -3e38f, mv1 = -3e38f, mv2 = -3e38f, mv3 = -3e38f;
    float lv0 = 0.f, lv1 = 0.f, lv2 = 0.f, lv3 = 0.f;
    mv0 = Mpart[(h * 4 + 0) * T + r]; lv0 = Lpart[(h * 4 + 0) * T + r];
    if (nch > 1) { mv1 = Mpart[(h * 4 + 1) * T + r]; lv1 = Lpart[(h * 4 + 1) * T + r]; }
    if (nch > 2) { mv2 = Mpart[(h * 4 + 2) * T + r]; lv2 = Lpart[(h * 4 + 2) * T + r]; }
    if (nch > 3) { mv3 = Mpart[(h * 4 + 3) * T + r]; lv3 = Lpart[(h * 4 + 3) * T + r]; }
    const float M = fmaxf(fmaxf(mv0, mv1), fmaxf(mv2, mv3));
    float w0 = __expf(mv0 - M), w1 = __expf(mv1 - M);
    float w2 = __expf(mv2 - M), w3 = __expf(mv3 - M);
    const float L = lv0 * w0 + lv1 * w1 + lv2 * w2 + lv3 * w3;
    const float invL = 1.0f / L;
    w0 *= invL; w1 *= invL; w2 *= invL; w3 *= invL;

    #pragma unroll
    for (int d = 0; d < 64; ++d) {
        float acc = Opart[((h * 4 + 0) * 64 + d) * T + r] * w0;
        if (nch > 1) acc = fmaf(Opart[((h * 4 + 1) * 64 + d) * T + r], w1, acc);
        if (nch > 2) acc = fmaf(Opart[((h * 4 + 2) * 64 + d) * T + r], w2, acc);
        if (nch > 3) acc = fmaf(Opart[((h * 4 + 3) * 64 + d) * T + r], w3, acc);
        AOT[(h * 64 + d) * T + r] = acc;
    }
}

// --------------------------------------------- O-proj + bias + residual
// out[c][t] = x[c][t] + o_b[c] + sum_o AOT[o][t] * o_w[c][o]
__global__ __launch_bounds__(256) void oproj_kernel(
    const float* __restrict__ AOT, const float* __restrict__ o_w,
    const float* __restrict__ o_b, const float* __restrict__ x,
    float* __restrict__ out)
{
    const int tid = threadIdx.x;
    const int tx = tid & 15, ty = tid >> 4;
    const int t0 = blockIdx.x * 64;
    const int c0 = blockIdx.y * 64;

    __shared__ float As[16][64];  // [o-local][t-local]
    __shared__ float Bs[16][68];  // [o-local][c-local], padded

    float acc[4][4] = {{0.f}};

    const int a_kc = tid >> 4;
    const int a_tt = (tid & 15) * 4;
    const int b_row = tid >> 2;        // c-local 0..63
    const int b_off = (tid & 3) * 4;   // o-local 0,4,8,12

    for (int k0 = 0; k0 < QDIM; k0 += 16) {
        const float4 av = *(const float4*)&AOT[(k0 + a_kc) * T + t0 + a_tt];
        const float4 bv = *(const float4*)&o_w[(c0 + b_row) * QDIM + k0 + b_off];
        __syncthreads();
        *(float4*)&As[a_kc][a_tt] = av;
        Bs[b_off + 0][b_row] = bv.x;
        Bs[b_off + 1][b_row] = bv.y;
        Bs[b_off + 2][b_row] = bv.z;
        Bs[b_off + 3][b_row] = bv.w;
        __syncthreads();
        #pragma unroll
        for (int kk = 0; kk < 16; ++kk) {
            const float4 a = *(const float4*)&As[kk][ty * 4];
            const float4 b = *(const float4*)&Bs[kk][tx * 4];
            acc[0][0] = fmaf(a.x, b.x, acc[0][0]);
            acc[0][1] = fmaf(a.x, b.y, acc[0][1]);
            acc[0][2] = fmaf(a.x, b.z, acc[0][2]);
            acc[0][3] = fmaf(a.x, b.w, acc[0][3]);
            acc[1][0] = fmaf(a.y, b.x, acc[1][0]);
            acc[1][1] = fmaf(a.y, b.y, acc[1][1]);
            acc[1][2] = fmaf(a.y, b.z, acc[1][2]);
            acc[1][3] = fmaf(a.y, b.w, acc[1][3]);
            acc[2][0] = fmaf(a.z, b.x, acc[2][0]);
            acc[2][1] = fmaf(a.z, b.y, acc[2][1]);
            acc[2][2] = fmaf(a.z, b.z, acc[2][2]);
            acc[2][3] = fmaf(a.z, b.w, acc[2][3]);
            acc[3][0] = fmaf(a.w, b.x, acc[3][0]);
            acc[3][1] = fmaf(a.w, b.y, acc[3][1]);
            acc[3][2] = fmaf(a.w, b.z, acc[3][2]);
            acc[3][3] = fmaf(a.w, b.w, acc[3][3]);
        }
    }

    const int t_base = t0 + ty * 4;
    #pragma unroll
    for (int j = 0; j < 4; ++j) {
        const int c = c0 + tx * 4 + j;
        const float ob = o_b[c];
        const float4 xr = *(const float4*)&x[c * T + t_base];
        float4 ov;
        ov.x = acc[0][j] + ob + xr.x;
        ov.y = acc[1][j] + ob + xr.y;
        ov.z = acc[2][j] + ob + xr.z;
        ov.w = acc[3][j] + ob + xr.w;
        *(float4*)&out[c * T + t_base] = ov;
    }
}

// ---------------------------------------------------------------- launcher
extern "C" void kernel_launch(void* const* d_in, const int* in_sizes, int n_in,
                              void* d_out, int out_size, void* d_ws, size_t ws_size,
                              hipStream_t stream) {
    const float* x        = (const float*)d_in[0];
    const float* rope_cos = (const float*)d_in[1];
    const float* rope_sin = (const float*)d_in[2];
    // d_in[3] attn_mask: unused (causal mask computed analytically)
    const float* norm_w   = (const float*)d_in[4];
    const float* qkv_w    = (const float*)d_in[5];
    const float* qkv_b    = (const float*)d_in[6];
    const float* o_w      = (const float*)d_in[7];
    const float* o_b      = (const float*)d_in[8];
    const float* sinks    = (const float*)d_in[9];
    float* out = (float*)d_out;

    float* ws    = (float*)d_ws;
    float* rpart = ws;                    // 10*T        = 20480
    float* rstd  = rpart + 20480;         // T           = 2048
    float* Qb    = rstd + 2048;           // NH*T*HD     = 1835008
    float* Kb    = Qb + 1835008;          // NKV*T*HD    = 262144
    float* Vb    = Kb + 262144;           // NKV*T*HD    = 262144
    float* AOT   = Vb + 262144;           // QDIM*T      = 1835008
    float* Opart = AOT + 1835008;         // NH*4*HD*T   = 7340032
    float* Mpart = Opart + 7340032;       // NH*4*T      = 114688
    float* Lpart = Mpart + 114688;        // NH*4*T      = 114688

    rstd_partial_kernel<<<dim3(8, 10), 256, 0, stream>>>(x, rpart);
    rstd_final_kernel<<<8, 256, 0, stream>>>(rpart, rstd);
    qkv_gemm_kernel<<<dim3(32, 18), 256, 0, stream>>>(
        x, norm_w, rstd, qkv_w, qkv_b, rope_cos, rope_sin, Qb, Kb, Vb);
    attn_partial_kernel<<<dim3(32, NH, 4), 64, 0, stream>>>(
        Qb, Kb, Vb, sinks, Opart, Mpart, Lpart);
    attn_combine_kernel<<<NH * T / 256, 256, 0, stream>>>(Opart, Mpart, Lpart, AOT);
    oproj_kernel<<<dim3(32, 10), 256, 0, stream>>>(AOT, o_w, o_b, x, out);
}

// Round 2
// 335.605 us; speedup vs baseline: 2.9814x; 2.9814x over previous
//
#include <hip/hip_runtime.h>
#include <math.h>

#define T 2048
#define DM 640
#define NH 14
#define NKV 2
#define HPK 7
#define HD 64
#define QDIM 896
#define QKV_DIM 1152

constexpr float QK_SCALE = 0.35355339059327373f; // 64^-0.25
constexpr float LN2F = 0.6931471805599453f;
constexpr float EPSF = 1e-5f;

typedef __attribute__((ext_vector_type(8))) short short8;   // 8 bf16 = 4 VGPR
typedef __attribute__((ext_vector_type(4))) float float4v;  // MFMA acc

static __device__ __forceinline__ unsigned short f2bf(float f) {
    union { float f; unsigned u; } v; v.f = f;
    unsigned r = v.u + 0x7fffu + ((v.u >> 16) & 1u);
    return (unsigned short)(r >> 16);
}
static __device__ __forceinline__ float bf2f(unsigned short s) {
    union { unsigned u; float f; } v; v.u = ((unsigned)s) << 16;
    return v.f;
}

// ---------------------------------------------------------------- RMSNorm rstd
__global__ __launch_bounds__(256) void rstd_partial_kernel(
    const float* __restrict__ x, float* __restrict__ rpart)
{
    const int t = blockIdx.x * 256 + threadIdx.x;
    const int cb = blockIdx.y;
    float ss = 0.f;
    #pragma unroll 8
    for (int i = 0; i < 64; ++i) {
        float v = x[(cb * 64 + i) * T + t];
        ss = fmaf(v, v, ss);
    }
    rpart[cb * T + t] = ss;
}

__global__ __launch_bounds__(256) void rstd_final_kernel(
    const float* __restrict__ rpart, float* __restrict__ rstd)
{
    const int t = blockIdx.x * 256 + threadIdx.x;
    float ss = 0.f;
    #pragma unroll
    for (int j = 0; j < 10; ++j) ss += rpart[j * T + t];
    rstd[t] = rsqrtf(ss * (1.0f / DM) + EPSF);
}

// ------------------------------------------------- QKV GEMM + bias + RoPE + scale
// Emits bf16 hi/lo planes: Qh/Ql [h][t][d], Kh/Kl [kvh][t][d], Vth/Vtl [kvh][d][t]
__global__ __launch_bounds__(256) void qkv_gemm_kernel(
    const float* __restrict__ x, const float* __restrict__ norm_w,
    const float* __restrict__ rstd, const float* __restrict__ qkv_w,
    const float* __restrict__ qkv_b, const float* __restrict__ rope_cos,
    const float* __restrict__ rope_sin,
    unsigned short* __restrict__ Qh, unsigned short* __restrict__ Ql,
    unsigned short* __restrict__ Kh, unsigned short* __restrict__ Kl,
    unsigned short* __restrict__ Vth, unsigned short* __restrict__ Vtl)
{
    const int tid = threadIdx.x;
    const int tx = tid & 15, ty = tid >> 4;
    const int t0 = blockIdx.x * 64;
    const int o0 = blockIdx.y * 64;

    __shared__ float As[16][64];
    __shared__ float Bs[16][68];

    float acc[4][4] = {{0.f}};

    const int a_kc = tid >> 4;
    const int a_tt = (tid & 15) * 4;
    const int b_row = tid >> 2;
    const int b_off = (tid & 3) * 4;

    const float4 rs = *(const float4*)&rstd[t0 + a_tt];

    for (int c0 = 0; c0 < DM; c0 += 16) {
        float4 av = *(const float4*)&x[(c0 + a_kc) * T + t0 + a_tt];
        const float nw = norm_w[c0 + a_kc];
        av.x *= nw * rs.x; av.y *= nw * rs.y; av.z *= nw * rs.z; av.w *= nw * rs.w;
        const float4 bv = *(const float4*)&qkv_w[(o0 + b_row) * DM + c0 + b_off];
        __syncthreads();
        *(float4*)&As[a_kc][a_tt] = av;
        Bs[b_off + 0][b_row] = bv.x;
        Bs[b_off + 1][b_row] = bv.y;
        Bs[b_off + 2][b_row] = bv.z;
        Bs[b_off + 3][b_row] = bv.w;
        __syncthreads();
        #pragma unroll
        for (int kk = 0; kk < 16; ++kk) {
            const float4 a = *(const float4*)&As[kk][ty * 4];
            const float4 b = *(const float4*)&Bs[kk][tx * 4];
            acc[0][0] = fmaf(a.x, b.x, acc[0][0]);
            acc[0][1] = fmaf(a.x, b.y, acc[0][1]);
            acc[0][2] = fmaf(a.x, b.z, acc[0][2]);
            acc[0][3] = fmaf(a.x, b.w, acc[0][3]);
            acc[1][0] = fmaf(a.y, b.x, acc[1][0]);
            acc[1][1] = fmaf(a.y, b.y, acc[1][1]);
            acc[1][2] = fmaf(a.y, b.z, acc[1][2]);
            acc[1][3] = fmaf(a.y, b.w, acc[1][3]);
            acc[2][0] = fmaf(a.z, b.x, acc[2][0]);
            acc[2][1] = fmaf(a.z, b.y, acc[2][1]);
            acc[2][2] = fmaf(a.z, b.z, acc[2][2]);
            acc[2][3] = fmaf(a.z, b.w, acc[2][3]);
            acc[3][0] = fmaf(a.w, b.x, acc[3][0]);
            acc[3][1] = fmaf(a.w, b.y, acc[3][1]);
            acc[3][2] = fmaf(a.w, b.z, acc[3][2]);
            acc[3][3] = fmaf(a.w, b.w, acc[3][3]);
        }
    }

    const int dloc = tx * 4;
    const int t_base = t0 + ty * 4;
    const float4 bias = *(const float4*)&qkv_b[o0 + dloc];
    const int by = blockIdx.y;

    if (by < 16) { // Q or K heads: rope + scale, store hi/lo
        #pragma unroll
        for (int i = 0; i < 4; ++i) {
            const int t = t_base + i;
            const float e0 = acc[i][0] + bias.x, d1 = acc[i][1] + bias.y;
            const float e2 = acc[i][2] + bias.z, d3 = acc[i][3] + bias.w;
            const float c0v = rope_cos[t * 32 + (dloc >> 1)];
            const float s0v = rope_sin[t * 32 + (dloc >> 1)];
            const float c1v = rope_cos[t * 32 + (dloc >> 1) + 1];
            const float s1v = rope_sin[t * 32 + (dloc >> 1) + 1];
            float r0 = (e0 * c0v - d1 * s0v) * QK_SCALE;
            float r1 = (d1 * c0v + e0 * s0v) * QK_SCALE;
            float r2 = (e2 * c1v - d3 * s1v) * QK_SCALE;
            float r3 = (d3 * c1v + e2 * s1v) * QK_SCALE;
            ushort4 hi, lo;
            hi.x = f2bf(r0); lo.x = f2bf(r0 - bf2f(hi.x));
            hi.y = f2bf(r1); lo.y = f2bf(r1 - bf2f(hi.y));
            hi.z = f2bf(r2); lo.z = f2bf(r2 - bf2f(hi.z));
            hi.w = f2bf(r3); lo.w = f2bf(r3 - bf2f(hi.w));
            if (by < 14) {
                const int h = by;
                *(ushort4*)&Qh[((size_t)(h * T + t)) * HD + dloc] = hi;
                *(ushort4*)&Ql[((size_t)(h * T + t)) * HD + dloc] = lo;
            } else {
                const int h = by - 14;
                *(ushort4*)&Kh[((size_t)(h * T + t)) * HD + dloc] = hi;
                *(ushort4*)&Kl[((size_t)(h * T + t)) * HD + dloc] = lo;
            }
        }
    } else { // V heads: store transposed (d-major) hi/lo
        const int h = by - 16;
        #pragma unroll
        for (int i = 0; i < 4; ++i) {
            const int t = t_base + i;
            float vals[4] = { acc[i][0] + bias.x, acc[i][1] + bias.y,
                              acc[i][2] + bias.z, acc[i][3] + bias.w };
            #pragma unroll
            for (int j = 0; j < 4; ++j) {
                unsigned short hi = f2bf(vals[j]);
                unsigned short lo = f2bf(vals[j] - bf2f(hi));
                Vth[((size_t)(h * HD + dloc + j)) * T + t] = hi;
                Vtl[((size_t)(h * HD + dloc + j)) * T + t] = lo;
            }
        }
    }
}

// --------------------------------------------- attention: MFMA flash, split-K
// block = 256 thr (4 waves x 16 q-rows), 64-key LDS tiles, hi/lo bf16 (3-term)
#define SK_H 0
#define SK_L 8192
#define SV_H 16384
#define SV_L 24576

__global__ __launch_bounds__(256) void attn_mfma_kernel(
    const unsigned short* __restrict__ Qh, const unsigned short* __restrict__ Ql,
    const unsigned short* __restrict__ Kh, const unsigned short* __restrict__ Kl,
    const unsigned short* __restrict__ Vth, const unsigned short* __restrict__ Vtl,
    const float* __restrict__ sinks,
    float* __restrict__ Opart, float* __restrict__ Mpart, float* __restrict__ Lpart)
{
    const int qt = blockIdx.x;
    const int h  = blockIdx.y;
    const int kc = blockIdx.z;
    if (qt < kc * 8) return;

    const int kvh = h / HPK;
    const int tid = threadIdx.x;
    const int wave = tid >> 6, lane = tid & 63;
    const int lg = lane >> 4, lq = lane & 15;
    const int qbase = qt * 64 + wave * 16;
    const int myq = qbase + lq;

    __shared__ __align__(16) unsigned char sm[32768];

    // Q B-frags (held all block): [kk][hi/lo]
    short8 qf[2][2];
    #pragma unroll
    for (int kk = 0; kk < 2; ++kk) {
        const size_t qoff = ((size_t)(h * T + myq)) * HD + kk * 32 + lg * 8;
        qf[kk][0] = *(const short8*)&Qh[qoff];
        qf[kk][1] = *(const short8*)&Ql[qoff];
    }

    float4v oacc[4];
    #pragma unroll
    for (int dt = 0; dt < 4; ++dt) oacc[dt] = (float4v)0.f;

    float m, l;
    if (kc == 0) { m = sinks[h] * LN2F; l = 1.0f; }
    else         { m = -3e38f;          l = 0.0f; }

    const unsigned short* Khp = Kh + ((size_t)kvh) * T * HD;
    const unsigned short* Klp = Kl + ((size_t)kvh) * T * HD;
    const unsigned short* Vhp = Vth + ((size_t)kvh) * HD * T;
    const unsigned short* Vlp = Vtl + ((size_t)kvh) * HD * T;

    const int kstart = kc * 512;
    const int kend = min(kstart + 512, qt * 64 + 64);

    for (int kb = kstart; kb < kend; kb += 64) {
        __syncthreads();
        // stage K(hi,lo)[64key][64d] and Vt(hi,lo)[64d][64key], XOR-swizzled rows
        #pragma unroll
        for (int rep = 0; rep < 2; ++rep) {
            const int ci = tid + rep * 256;       // 0..511
            const int row = ci >> 3, cc = ci & 7;
            const int dst = row * 128 + ((cc * 16) ^ ((row & 7) << 4));
            *(uint4*)(sm + SK_H + dst) = *(const uint4*)(Khp + (size_t)(kb + row) * HD + cc * 8);
            *(uint4*)(sm + SK_L + dst) = *(const uint4*)(Klp + (size_t)(kb + row) * HD + cc * 8);
            *(uint4*)(sm + SV_H + dst) = *(const uint4*)(Vhp + (size_t)row * T + kb + cc * 8);
            *(uint4*)(sm + SV_L + dst) = *(const uint4*)(Vlp + (size_t)row * T + kb + cc * 8);
        }
        __syncthreads();

        // ---- S^T = K . Q^T : 4 key-tiles (M=key16), N=16 q, K-dim d=64
        float4v st[4];
        #pragma unroll
        for (int t = 0; t < 4; ++t) st[t] = (float4v)0.f;
        #pragma unroll
        for (int t = 0; t < 4; ++t) {
            const int row = t * 16 + lq;
            const int sw = (row & 7) << 4;
            #pragma unroll
            for (int kk = 0; kk < 2; ++kk) {
                const int col = (kk * 64 + lg * 16) ^ sw;
                short8 ah = *(const short8*)(sm + SK_H + row * 128 + col);
                short8 al = *(const short8*)(sm + SK_L + row * 128 + col);
                st[t] = __builtin_amdgcn_mfma_f32_16x16x32_bf16(ah, qf[kk][0], st[t], 0, 0, 0);
                st[t] = __builtin_amdgcn_mfma_f32_16x16x32_bf16(ah, qf[kk][1], st[t], 0, 0, 0);
                st[t] = __builtin_amdgcn_mfma_f32_16x16x32_bf16(al, qf[kk][0], st[t], 0, 0, 0);
            }
        }

        // ---- causal mask + online softmax (lane owns q-col = myq)
        float pmax = -3e38f;
        #pragma unroll
        for (int t = 0; t < 4; ++t) {
            #pragma unroll
            for (int j = 0; j < 4; ++j) {
                const int key = kb + 16 * t + 4 * lg + j;
                float s = st[t][j] + ((key > myq) ? -1e9f : 0.f);
                st[t][j] = s;
                pmax = fmaxf(pmax, s);
            }
        }
        pmax = fmaxf(pmax, __shfl_xor(pmax, 16));
        pmax = fmaxf(pmax, __shfl_xor(pmax, 32));
        const float mnew = fmaxf(m, pmax);
        const float corr = __expf(m - mnew);
        float psum = 0.f;
        #pragma unroll
        for (int t = 0; t < 4; ++t) {
            #pragma unroll
            for (int j = 0; j < 4; ++j) {
                const float p = __expf(st[t][j] - mnew);
                st[t][j] = p;
                psum += p;
            }
        }
        psum += __shfl_xor(psum, 16);
        psum += __shfl_xor(psum, 32);
        l = l * corr + psum;
        m = mnew;
        #pragma unroll
        for (int dt = 0; dt < 4; ++dt) oacc[dt] *= corr;

        // ---- O^T += V^T . P^T : per 32-key chunk build P frags via shuffles
        #pragma unroll
        for (int c = 0; c < 2; ++c) {
            float pv[8];
            #pragma unroll
            for (int i = 0; i < 8; ++i) {
                const int j = i & 3;
                const int gsel = ((lg * 8 + i) >> 2) & 3;
                const int src = (gsel << 4) | lq;
                const float v0 = __shfl(st[2 * c + 0][j], src);
                const float v1 = __shfl(st[2 * c + 1][j], src);
                pv[i] = (lg >= 2) ? v1 : v0;
            }
            short8 ph, pl;
            #pragma unroll
            for (int i = 0; i < 8; ++i) {
                const unsigned short hi = f2bf(pv[i]);
                ph[i] = (short)hi;
                pl[i] = (short)f2bf(pv[i] - bf2f(hi));
            }
            #pragma unroll
            for (int dt = 0; dt < 4; ++dt) {
                const int row = dt * 16 + lq;
                const int col = (c * 64 + lg * 16) ^ ((row & 7) << 4);
                short8 vh = *(const short8*)(sm + SV_H + row * 128 + col);
                short8 vl = *(const short8*)(sm + SV_L + row * 128 + col);
                oacc[dt] = __builtin_amdgcn_mfma_f32_16x16x32_bf16(vh, ph, oacc[dt], 0, 0, 0);
                oacc[dt] = __builtin_amdgcn_mfma_f32_16x16x32_bf16(vh, pl, oacc[dt], 0, 0, 0);
                oacc[dt] = __builtin_amdgcn_mfma_f32_16x16x32_bf16(vl, ph, oacc[dt], 0, 0, 0);
            }
        }
    }

    // ---- store partials (O^T layout: lane q = col, rows = d)
    const int r = qbase + lq;
    const int pb = (h * 4 + kc) * 64;
    #pragma unroll
    for (int dt = 0; dt < 4; ++dt) {
        #pragma unroll
        for (int j = 0; j < 4; ++j) {
            const int d = dt * 16 + lg * 4 + j;
            Opart[(size_t)(pb + d) * T + r] = oacc[dt][j];
        }
    }
    if (lane < 16) {
        Mpart[(size_t)(h * 4 + kc) * T + r] = m;
        Lpart[(size_t)(h * 4 + kc) * T + r] = l;
    }
}

// --------------------------------------------- attention: combine partials
__global__ __launch_bounds__(256) void attn_combine_kernel(
    const float* __restrict__ Opart, const float* __restrict__ Mpart,
    const float* __restrict__ Lpart, float* __restrict__ AOT)
{
    const int idx = blockIdx.x * 256 + threadIdx.x;
    const int h = idx >> 11;
    const int r = idx & (T - 1);
    const int nch = (r >> 9) + 1;

    float mv0 = -3e38f, mv1 = -3e38f, mv2 = -3e38f, mv3 = -3e38f;
    float lv0 = 0.f, lv1 = 0.f, lv2 = 0.f, lv3 = 0.f;
    mv0 = Mpart[(h * 4 + 0) * T + r]; lv0 = Lpart[(h * 4 + 0) * T + r];
    if (nch > 1) { mv1 = Mpart[(h * 4 + 1) * T + r]; lv1 = Lpart[(h * 4 + 1) * T + r]; }
    if (nch > 2) { mv2 = Mpart[(h * 4 + 2) * T + r]; lv2 = Lpart[(h * 4 + 2) * T + r]; }
    if (nch > 3) { mv3 = Mpart[(h * 4 + 3) * T + r]; lv3 = Lpart[(h * 4 + 3) * T + r]; }
    const float M = fmaxf(fmaxf(mv0, mv1), fmaxf(mv2, mv3));
    float w0 = __expf(mv0 - M), w1 = __expf(mv1 - M);
    float w2 = __expf(mv2 - M), w3 = __expf(mv3 - M);
    const float L = lv0 * w0 + lv1 * w1 + lv2 * w2 + lv3 * w3;
    const float invL = 1.0f / L;
    w0 *= invL; w1 *= invL; w2 *= invL; w3 *= invL;

    #pragma unroll
    for (int d = 0; d < 64; ++d) {
        float acc = Opart[((h * 4 + 0) * 64 + d) * (size_t)T + r] * w0;
        if (nch > 1) acc = fmaf(Opart[((h * 4 + 1) * 64 + d) * (size_t)T + r], w1, acc);
        if (nch > 2) acc = fmaf(Opart[((h * 4 + 2) * 64 + d) * (size_t)T + r], w2, acc);
        if (nch > 3) acc = fmaf(Opart[((h * 4 + 3) * 64 + d) * (size_t)T + r], w3, acc);
        AOT[(h * 64 + d) * (size_t)T + r] = acc;
    }
}

// --------------------------------------------- O-proj + bias + residual
__global__ __launch_bounds__(256) void oproj_kernel(
    const float* __restrict__ AOT, const float* __restrict__ o_w,
    const float* __restrict__ o_b, const float* __restrict__ x,
    float* __restrict__ out)
{
    const int tid = threadIdx.x;
    const int tx = tid & 15, ty = tid >> 4;
    const int t0 = blockIdx.x * 64;
    const int c0 = blockIdx.y * 64;

    __shared__ float As[16][64];
    __shared__ float Bs[16][68];

    float acc[4][4] = {{0.f}};

    const int a_kc = tid >> 4;
    const int a_tt = (tid & 15) * 4;
    const int b_row = tid >> 2;
    const int b_off = (tid & 3) * 4;

    for (int k0 = 0; k0 < QDIM; k0 += 16) {
        const float4 av = *(const float4*)&AOT[(k0 + a_kc) * T + t0 + a_tt];
        const float4 bv = *(const float4*)&o_w[(c0 + b_row) * QDIM + k0 + b_off];
        __syncthreads();
        *(float4*)&As[a_kc][a_tt] = av;
        Bs[b_off + 0][b_row] = bv.x;
        Bs[b_off + 1][b_row] = bv.y;
        Bs[b_off + 2][b_row] = bv.z;
        Bs[b_off + 3][b_row] = bv.w;
        __syncthreads();
        #pragma unroll
        for (int kk = 0; kk < 16; ++kk) {
            const float4 a = *(const float4*)&As[kk][ty * 4];
            const float4 b = *(const float4*)&Bs[kk][tx * 4];
            acc[0][0] = fmaf(a.x, b.x, acc[0][0]);
            acc[0][1] = fmaf(a.x, b.y, acc[0][1]);
            acc[0][2] = fmaf(a.x, b.z, acc[0][2]);
            acc[0][3] = fmaf(a.x, b.w, acc[0][3]);
            acc[1][0] = fmaf(a.y, b.x, acc[1][0]);
            acc[1][1] = fmaf(a.y, b.y, acc[1][1]);
            acc[1][2] = fmaf(a.y, b.z, acc[1][2]);
            acc[1][3] = fmaf(a.y, b.w, acc[1][3]);
            acc[2][0] = fmaf(a.z, b.x, acc[2][0]);
            acc[2][1] = fmaf(a.z, b.y, acc[2][1]);
            acc[2][2] = fmaf(a.z, b.z, acc[2][2]);
            acc[2][3] = fmaf(a.z, b.w, acc[2][3]);
            acc[3][0] = fmaf(a.w, b.x, acc[3][0]);
            acc[3][1] = fmaf(a.w, b.y, acc[3][1]);
            acc[3][2] = fmaf(a.w, b.z, acc[3][2]);
            acc[3][3] = fmaf(a.w, b.w, acc[3][3]);
        }
    }

    const int t_base = t0 + ty * 4;
    #pragma unroll
    for (int j = 0; j < 4; ++j) {
        const int c = c0 + tx * 4 + j;
        const float ob = o_b[c];
        const float4 xr = *(const float4*)&x[c * T + t_base];
        float4 ov;
        ov.x = acc[0][j] + ob + xr.x;
        ov.y = acc[1][j] + ob + xr.y;
        ov.z = acc[2][j] + ob + xr.z;
        ov.w = acc[3][j] + ob + xr.w;
        *(float4*)&out[c * T + t_base] = ov;
    }
}

// ---------------------------------------------------------------- launcher
extern "C" void kernel_launch(void* const* d_in, const int* in_sizes, int n_in,
                              void* d_out, int out_size, void* d_ws, size_t ws_size,
                              hipStream_t stream) {
    const float* x        = (const float*)d_in[0];
    const float* rope_cos = (const float*)d_in[1];
    const float* rope_sin = (const float*)d_in[2];
    const float* norm_w   = (const float*)d_in[4];
    const float* qkv_w    = (const float*)d_in[5];
    const float* qkv_b    = (const float*)d_in[6];
    const float* o_w      = (const float*)d_in[7];
    const float* o_b      = (const float*)d_in[8];
    const float* sinks    = (const float*)d_in[9];
    float* out = (float*)d_out;

    // fp32 region
    float* ws    = (float*)d_ws;
    float* rpart = ws;                       // 20480
    float* rstd  = rpart + 20480;            // 2048
    float* AOT   = rstd + 2048;              // 1835008
    float* Opart = AOT + 1835008;            // 7340032
    float* Mpart = Opart + 7340032;          // 114688
    float* Lpart = Mpart + 114688;           // 114688
    // bf16 region
    unsigned short* bws = (unsigned short*)(Lpart + 114688);
    unsigned short* Qh  = bws;               // NH*T*HD  = 1835008
    unsigned short* Ql  = Qh  + 1835008;
    unsigned short* Kh  = Ql  + 1835008;     // NKV*T*HD = 262144
    unsigned short* Kl  = Kh  + 262144;
    unsigned short* Vth = Kl  + 262144;
    unsigned short* Vtl = Vth + 262144;

    rstd_partial_kernel<<<dim3(8, 10), 256, 0, stream>>>(x, rpart);
    rstd_final_kernel<<<8, 256, 0, stream>>>(rpart, rstd);
    qkv_gemm_kernel<<<dim3(32, 18), 256, 0, stream>>>(
        x, norm_w, rstd, qkv_w, qkv_b, rope_cos, rope_sin, Qh, Ql, Kh, Kl, Vth, Vtl);
    attn_mfma_kernel<<<dim3(32, NH, 4), 256, 0, stream>>>(
        Qh, Ql, Kh, Kl, Vth, Vtl, sinks, Opart, Mpart, Lpart);
    attn_combine_kernel<<<NH * T / 256, 256, 0, stream>>>(Opart, Mpart, Lpart, AOT);
    oproj_kernel<<<dim3(32, 10), 256, 0, stream>>>(AOT, o_w, o_b, x, out);
}

// Round 3
// 267.743 us; speedup vs baseline: 3.7371x; 1.2535x over previous
//
#include <hip/hip_runtime.h>
#include <math.h>

#define T 2048
#define DM 640
#define NH 14
#define NKV 2
#define HPK 7
#define HD 64
#define QDIM 896
#define QKV_DIM 1152

constexpr float QK_SCALE = 0.35355339059327373f; // 64^-0.25
constexpr float LN2F = 0.6931471805599453f;
constexpr float EPSF = 1e-5f;

typedef __attribute__((ext_vector_type(8))) short short8;   // 8 bf16 = 4 VGPR
typedef __attribute__((ext_vector_type(4))) float float4v;  // MFMA acc

static __device__ __forceinline__ unsigned short f2bf(float f) {
    union { float f; unsigned u; } v; v.f = f;
    unsigned r = v.u + 0x7fffu + ((v.u >> 16) & 1u);
    return (unsigned short)(r >> 16);
}
static __device__ __forceinline__ float bf2f(unsigned short s) {
    union { unsigned u; float f; } v; v.u = ((unsigned)s) << 16;
    return v.f;
}

// ---------------------------------------------------------------- RMSNorm rstd
__global__ __launch_bounds__(256) void rstd_partial_kernel(
    const float* __restrict__ x, float* __restrict__ rpart)
{
    const int t = blockIdx.x * 256 + threadIdx.x;
    const int cb = blockIdx.y;
    float ss = 0.f;
    #pragma unroll 8
    for (int i = 0; i < 64; ++i) {
        float v = x[(cb * 64 + i) * T + t];
        ss = fmaf(v, v, ss);
    }
    rpart[cb * T + t] = ss;
}

__global__ __launch_bounds__(256) void rstd_final_kernel(
    const float* __restrict__ rpart, float* __restrict__ rstd)
{
    const int t = blockIdx.x * 256 + threadIdx.x;
    float ss = 0.f;
    #pragma unroll
    for (int j = 0; j < 10; ++j) ss += rpart[j * T + t];
    rstd[t] = rsqrtf(ss * (1.0f / DM) + EPSF);
}

// ------------------------------------------------- fp32 -> bf16 hi/lo cast
__global__ __launch_bounds__(256) void cast_hilo_kernel(
    const float* __restrict__ in, unsigned short* __restrict__ hi,
    unsigned short* __restrict__ lo, int n4)
{
    for (int i = blockIdx.x * 256 + threadIdx.x; i < n4; i += gridDim.x * 256) {
        const float4 v = ((const float4*)in)[i];
        ushort4 h, l;
        h.x = f2bf(v.x); l.x = f2bf(v.x - bf2f(h.x));
        h.y = f2bf(v.y); l.y = f2bf(v.y - bf2f(h.y));
        h.z = f2bf(v.z); l.z = f2bf(v.z - bf2f(h.z));
        h.w = f2bf(v.w); l.w = f2bf(v.w - bf2f(h.w));
        ((ushort4*)hi)[i] = h;
        ((ushort4*)lo)[i] = l;
    }
}

// ------------------------------------------------- normed x, transposed to [t][c]
__global__ __launch_bounds__(256) void xnorm_kernel(
    const float* __restrict__ x, const float* __restrict__ norm_w,
    const float* __restrict__ rstd,
    unsigned short* __restrict__ XnH, unsigned short* __restrict__ XnL)
{
    const int tid = threadIdx.x;
    const int t0 = blockIdx.x * 64;
    const int c0 = blockIdx.y * 64;
    __shared__ float xs[64][65];

    #pragma unroll
    for (int it = 0; it < 4; ++it) {
        const int r = (tid >> 4) + it * 16;      // c-local
        const int cl = (tid & 15) * 4;           // t-local
        const float4 v = *(const float4*)&x[(size_t)(c0 + r) * T + t0 + cl];
        xs[r][cl + 0] = v.x; xs[r][cl + 1] = v.y;
        xs[r][cl + 2] = v.z; xs[r][cl + 3] = v.w;
    }
    __syncthreads();
    #pragma unroll
    for (int it = 0; it < 4; ++it) {
        const int tr = (tid >> 4) + it * 16;     // t-local
        const int cl = (tid & 15) * 4;           // c-local
        const float rs = rstd[t0 + tr];
        ushort4 h, l;
        float v0 = xs[cl + 0][tr] * norm_w[c0 + cl + 0] * rs;
        float v1 = xs[cl + 1][tr] * norm_w[c0 + cl + 1] * rs;
        float v2 = xs[cl + 2][tr] * norm_w[c0 + cl + 2] * rs;
        float v3 = xs[cl + 3][tr] * norm_w[c0 + cl + 3] * rs;
        h.x = f2bf(v0); l.x = f2bf(v0 - bf2f(h.x));
        h.y = f2bf(v1); l.y = f2bf(v1 - bf2f(h.y));
        h.z = f2bf(v2); l.z = f2bf(v2 - bf2f(h.z));
        h.w = f2bf(v3); l.w = f2bf(v3 - bf2f(h.w));
        *(ushort4*)&XnH[(size_t)(t0 + tr) * DM + c0 + cl] = h;
        *(ushort4*)&XnL[(size_t)(t0 + tr) * DM + c0 + cl] = l;
    }
}

// ------------------------------------------------- QKV MFMA GEMM (+bias+RoPE)
// Computes Out^T: M = o (qkv row), N = t. A = W[o][c], B = Xn[t][c].
#define QSX_H 0
#define QSX_L 8192
#define QSW_H 16384
#define QSW_L 24576

__global__ __launch_bounds__(256) void qkv_mfma_kernel(
    const unsigned short* __restrict__ XnH, const unsigned short* __restrict__ XnL,
    const unsigned short* __restrict__ WH, const unsigned short* __restrict__ WL,
    const float* __restrict__ qkv_b, const float* __restrict__ rope_cos,
    const float* __restrict__ rope_sin,
    unsigned short* __restrict__ Qh, unsigned short* __restrict__ Ql,
    unsigned short* __restrict__ Kh, unsigned short* __restrict__ Kl,
    unsigned short* __restrict__ Vth, unsigned short* __restrict__ Vtl)
{
    const int t0 = blockIdx.x * 64;
    const int o0 = blockIdx.y * 64;
    const int tid = threadIdx.x;
    const int wave = tid >> 6, lane = tid & 63;
    const int lg = lane >> 4, lq = lane & 15;
    const int wr = wave >> 1, wc = wave & 1;   // o-half, t-half

    __shared__ __align__(16) unsigned char sm[32768];

    float4v acc[2][2];
    acc[0][0] = (float4v)0.f; acc[0][1] = (float4v)0.f;
    acc[1][0] = (float4v)0.f; acc[1][1] = (float4v)0.f;

    for (int c0 = 0; c0 < DM; c0 += 64) {
        __syncthreads();
        #pragma unroll
        for (int rep = 0; rep < 2; ++rep) {
            const int ci = tid + rep * 256;
            const int row = ci >> 3, cc = ci & 7;
            const int dst = row * 128 + ((cc * 16) ^ ((row & 7) << 4));
            *(uint4*)(sm + QSX_H + dst) = *(const uint4*)&XnH[(size_t)(t0 + row) * DM + c0 + cc * 8];
            *(uint4*)(sm + QSX_L + dst) = *(const uint4*)&XnL[(size_t)(t0 + row) * DM + c0 + cc * 8];
            *(uint4*)(sm + QSW_H + dst) = *(const uint4*)&WH[(size_t)(o0 + row) * DM + c0 + cc * 8];
            *(uint4*)(sm + QSW_L + dst) = *(const uint4*)&WL[(size_t)(o0 + row) * DM + c0 + cc * 8];
        }
        __syncthreads();
        #pragma unroll
        for (int kk = 0; kk < 2; ++kk) {
            short8 ah[2], al[2], bh[2], bl[2];
            #pragma unroll
            for (int nt = 0; nt < 2; ++nt) {
                const int row = wc * 32 + nt * 16 + lq;
                const int col = (kk * 64 + lg * 16) ^ ((row & 7) << 4);
                bh[nt] = *(const short8*)(sm + QSX_H + row * 128 + col);
                bl[nt] = *(const short8*)(sm + QSX_L + row * 128 + col);
            }
            #pragma unroll
            for (int mt = 0; mt < 2; ++mt) {
                const int row = wr * 32 + mt * 16 + lq;
                const int col = (kk * 64 + lg * 16) ^ ((row & 7) << 4);
                ah[mt] = *(const short8*)(sm + QSW_H + row * 128 + col);
                al[mt] = *(const short8*)(sm + QSW_L + row * 128 + col);
            }
            #pragma unroll
            for (int mt = 0; mt < 2; ++mt) {
                #pragma unroll
                for (int nt = 0; nt < 2; ++nt) {
                    acc[mt][nt] = __builtin_amdgcn_mfma_f32_16x16x32_bf16(ah[mt], bh[nt], acc[mt][nt], 0, 0, 0);
                    acc[mt][nt] = __builtin_amdgcn_mfma_f32_16x16x32_bf16(ah[mt], bl[nt], acc[mt][nt], 0, 0, 0);
                    acc[mt][nt] = __builtin_amdgcn_mfma_f32_16x16x32_bf16(al[mt], bh[nt], acc[mt][nt], 0, 0, 0);
                }
            }
        }
    }

    // epilogue: C[row=o][col=t]; lane col t = lq, rows d0+j
    const int by = blockIdx.y;
    #pragma unroll
    for (int mt = 0; mt < 2; ++mt) {
        const int d0 = wr * 32 + mt * 16 + lg * 4;  // o-local base
        #pragma unroll
        for (int nt = 0; nt < 2; ++nt) {
            const int t = t0 + wc * 32 + nt * 16 + lq;
            if (by < 16) { // Q or K: bias + rope + scale
                const float e0 = acc[mt][nt][0] + qkv_b[o0 + d0 + 0];
                const float d1 = acc[mt][nt][1] + qkv_b[o0 + d0 + 1];
                const float e2 = acc[mt][nt][2] + qkv_b[o0 + d0 + 2];
                const float d3 = acc[mt][nt][3] + qkv_b[o0 + d0 + 3];
                const float c0v = rope_cos[t * 32 + (d0 >> 1)];
                const float s0v = rope_sin[t * 32 + (d0 >> 1)];
                const float c1v = rope_cos[t * 32 + (d0 >> 1) + 1];
                const float s1v = rope_sin[t * 32 + (d0 >> 1) + 1];
                const float r0 = (e0 * c0v - d1 * s0v) * QK_SCALE;
                const float r1 = (d1 * c0v + e0 * s0v) * QK_SCALE;
                const float r2 = (e2 * c1v - d3 * s1v) * QK_SCALE;
                const float r3 = (d3 * c1v + e2 * s1v) * QK_SCALE;
                ushort4 h, l;
                h.x = f2bf(r0); l.x = f2bf(r0 - bf2f(h.x));
                h.y = f2bf(r1); l.y = f2bf(r1 - bf2f(h.y));
                h.z = f2bf(r2); l.z = f2bf(r2 - bf2f(h.z));
                h.w = f2bf(r3); l.w = f2bf(r3 - bf2f(h.w));
                if (by < 14) {
                    *(ushort4*)&Qh[((size_t)(by * T + t)) * HD + d0] = h;
                    *(ushort4*)&Ql[((size_t)(by * T + t)) * HD + d0] = l;
                } else {
                    const int h2 = by - 14;
                    *(ushort4*)&Kh[((size_t)(h2 * T + t)) * HD + d0] = h;
                    *(ushort4*)&Kl[((size_t)(h2 * T + t)) * HD + d0] = l;
                }
            } else { // V: bias only, store d-major
                const int h2 = by - 16;
                #pragma unroll
                for (int j = 0; j < 4; ++j) {
                    const float val = acc[mt][nt][j] + qkv_b[o0 + d0 + j];
                    const unsigned short hh = f2bf(val);
                    Vth[((size_t)(h2 * HD + d0 + j)) * T + t] = hh;
                    Vtl[((size_t)(h2 * HD + d0 + j)) * T + t] = f2bf(val - bf2f(hh));
                }
            }
        }
    }
}

// --------------------------------------------- attention: MFMA flash, split-K
#define SK_H 0
#define SK_L 8192
#define SV_H 16384
#define SV_L 24576

__global__ __launch_bounds__(256) void attn_mfma_kernel(
    const unsigned short* __restrict__ Qh, const unsigned short* __restrict__ Ql,
    const unsigned short* __restrict__ Kh, const unsigned short* __restrict__ Kl,
    const unsigned short* __restrict__ Vth, const unsigned short* __restrict__ Vtl,
    const float* __restrict__ sinks,
    float* __restrict__ Opart, float* __restrict__ Mpart, float* __restrict__ Lpart)
{
    const int qt = blockIdx.x;
    const int h  = blockIdx.y;
    const int kc = blockIdx.z;
    if (qt < kc * 8) return;

    const int kvh = h / HPK;
    const int tid = threadIdx.x;
    const int wave = tid >> 6, lane = tid & 63;
    const int lg = lane >> 4, lq = lane & 15;
    const int qbase = qt * 64 + wave * 16;
    const int myq = qbase + lq;

    __shared__ __align__(16) unsigned char sm[32768];

    short8 qf[2][2];
    #pragma unroll
    for (int kk = 0; kk < 2; ++kk) {
        const size_t qoff = ((size_t)(h * T + myq)) * HD + kk * 32 + lg * 8;
        qf[kk][0] = *(const short8*)&Qh[qoff];
        qf[kk][1] = *(const short8*)&Ql[qoff];
    }

    float4v oacc[4];
    #pragma unroll
    for (int dt = 0; dt < 4; ++dt) oacc[dt] = (float4v)0.f;

    float m, l;
    if (kc == 0) { m = sinks[h] * LN2F; l = 1.0f; }
    else         { m = -3e38f;          l = 0.0f; }

    const unsigned short* Khp = Kh + ((size_t)kvh) * T * HD;
    const unsigned short* Klp = Kl + ((size_t)kvh) * T * HD;
    const unsigned short* Vhp = Vth + ((size_t)kvh) * HD * T;
    const unsigned short* Vlp = Vtl + ((size_t)kvh) * HD * T;

    const int kstart = kc * 512;
    const int kend = min(kstart + 512, qt * 64 + 64);

    for (int kb = kstart; kb < kend; kb += 64) {
        __syncthreads();
        #pragma unroll
        for (int rep = 0; rep < 2; ++rep) {
            const int ci = tid + rep * 256;
            const int row = ci >> 3, cc = ci & 7;
            const int dst = row * 128 + ((cc * 16) ^ ((row & 7) << 4));
            *(uint4*)(sm + SK_H + dst) = *(const uint4*)(Khp + (size_t)(kb + row) * HD + cc * 8);
            *(uint4*)(sm + SK_L + dst) = *(const uint4*)(Klp + (size_t)(kb + row) * HD + cc * 8);
            *(uint4*)(sm + SV_H + dst) = *(const uint4*)(Vhp + (size_t)row * T + kb + cc * 8);
            *(uint4*)(sm + SV_L + dst) = *(const uint4*)(Vlp + (size_t)row * T + kb + cc * 8);
        }
        __syncthreads();

        float4v st[4];
        #pragma unroll
        for (int t = 0; t < 4; ++t) st[t] = (float4v)0.f;
        #pragma unroll
        for (int t = 0; t < 4; ++t) {
            const int row = t * 16 + lq;
            const int sw = (row & 7) << 4;
            #pragma unroll
            for (int kk = 0; kk < 2; ++kk) {
                const int col = (kk * 64 + lg * 16) ^ sw;
                short8 ah = *(const short8*)(sm + SK_H + row * 128 + col);
                short8 al = *(const short8*)(sm + SK_L + row * 128 + col);
                st[t] = __builtin_amdgcn_mfma_f32_16x16x32_bf16(ah, qf[kk][0], st[t], 0, 0, 0);
                st[t] = __builtin_amdgcn_mfma_f32_16x16x32_bf16(ah, qf[kk][1], st[t], 0, 0, 0);
                st[t] = __builtin_amdgcn_mfma_f32_16x16x32_bf16(al, qf[kk][0], st[t], 0, 0, 0);
            }
        }

        float pmax = -3e38f;
        #pragma unroll
        for (int t = 0; t < 4; ++t) {
            #pragma unroll
            for (int j = 0; j < 4; ++j) {
                const int key = kb + 16 * t + 4 * lg + j;
                float s = st[t][j] + ((key > myq) ? -1e9f : 0.f);
                st[t][j] = s;
                pmax = fmaxf(pmax, s);
            }
        }
        pmax = fmaxf(pmax, __shfl_xor(pmax, 16));
        pmax = fmaxf(pmax, __shfl_xor(pmax, 32));
        const float mnew = fmaxf(m, pmax);
        const float corr = __expf(m - mnew);
        float psum = 0.f;
        #pragma unroll
        for (int t = 0; t < 4; ++t) {
            #pragma unroll
            for (int j = 0; j < 4; ++j) {
                const float p = __expf(st[t][j] - mnew);
                st[t][j] = p;
                psum += p;
            }
        }
        psum += __shfl_xor(psum, 16);
        psum += __shfl_xor(psum, 32);
        l = l * corr + psum;
        m = mnew;
        #pragma unroll
        for (int dt = 0; dt < 4; ++dt) oacc[dt] *= corr;

        #pragma unroll
        for (int c = 0; c < 2; ++c) {
            float pv[8];
            #pragma unroll
            for (int i = 0; i < 8; ++i) {
                const int j = i & 3;
                const int gsel = ((lg * 8 + i) >> 2) & 3;
                const int src = (gsel << 4) | lq;
                const float v0 = __shfl(st[2 * c + 0][j], src);
                const float v1 = __shfl(st[2 * c + 1][j], src);
                pv[i] = (lg >= 2) ? v1 : v0;
            }
            short8 ph, pl;
            #pragma unroll
            for (int i = 0; i < 8; ++i) {
                const unsigned short hi = f2bf(pv[i]);
                ph[i] = (short)hi;
                pl[i] = (short)f2bf(pv[i] - bf2f(hi));
            }
            #pragma unroll
            for (int dt = 0; dt < 4; ++dt) {
                const int row = dt * 16 + lq;
                const int col = (c * 64 + lg * 16) ^ ((row & 7) << 4);
                short8 vh = *(const short8*)(sm + SV_H + row * 128 + col);
                short8 vl = *(const short8*)(sm + SV_L + row * 128 + col);
                oacc[dt] = __builtin_amdgcn_mfma_f32_16x16x32_bf16(vh, ph, oacc[dt], 0, 0, 0);
                oacc[dt] = __builtin_amdgcn_mfma_f32_16x16x32_bf16(vh, pl, oacc[dt], 0, 0, 0);
                oacc[dt] = __builtin_amdgcn_mfma_f32_16x16x32_bf16(vl, ph, oacc[dt], 0, 0, 0);
            }
        }
    }

    const int r = qbase + lq;
    const int pb = (h * 4 + kc) * 64;
    #pragma unroll
    for (int dt = 0; dt < 4; ++dt) {
        #pragma unroll
        for (int j = 0; j < 4; ++j) {
            const int d = dt * 16 + lg * 4 + j;
            Opart[(size_t)(pb + d) * T + r] = oacc[dt][j];
        }
    }
    if (lane < 16) {
        Mpart[(size_t)(h * 4 + kc) * T + r] = m;
        Lpart[(size_t)(h * 4 + kc) * T + r] = l;
    }
}

// --------------------------------------------- attention: combine -> bf16 AO[t][o]
__global__ __launch_bounds__(256) void attn_combine_kernel(
    const float* __restrict__ Opart, const float* __restrict__ Mpart,
    const float* __restrict__ Lpart,
    unsigned short* __restrict__ AOH, unsigned short* __restrict__ AOL)
{
    const int idx = blockIdx.x * 256 + threadIdx.x;
    const int h = idx >> 11;
    const int r = idx & (T - 1);
    const int nch = (r >> 9) + 1;

    float mv0, mv1 = -3e38f, mv2 = -3e38f, mv3 = -3e38f;
    float lv0, lv1 = 0.f, lv2 = 0.f, lv3 = 0.f;
    mv0 = Mpart[(h * 4 + 0) * T + r]; lv0 = Lpart[(h * 4 + 0) * T + r];
    if (nch > 1) { mv1 = Mpart[(h * 4 + 1) * T + r]; lv1 = Lpart[(h * 4 + 1) * T + r]; }
    if (nch > 2) { mv2 = Mpart[(h * 4 + 2) * T + r]; lv2 = Lpart[(h * 4 + 2) * T + r]; }
    if (nch > 3) { mv3 = Mpart[(h * 4 + 3) * T + r]; lv3 = Lpart[(h * 4 + 3) * T + r]; }
    const float M = fmaxf(fmaxf(mv0, mv1), fmaxf(mv2, mv3));
    float w0 = __expf(mv0 - M), w1 = __expf(mv1 - M);
    float w2 = __expf(mv2 - M), w3 = __expf(mv3 - M);
    const float L = lv0 * w0 + lv1 * w1 + lv2 * w2 + lv3 * w3;
    const float invL = 1.0f / L;
    w0 *= invL; w1 *= invL; w2 *= invL; w3 *= invL;

    #pragma unroll
    for (int d4 = 0; d4 < 16; ++d4) {
        ushort4 hh, ll;
        #pragma unroll
        for (int j = 0; j < 4; ++j) {
            const int d = d4 * 4 + j;
            float acc = Opart[((h * 4 + 0) * 64 + d) * (size_t)T + r] * w0;
            if (nch > 1) acc = fmaf(Opart[((h * 4 + 1) * 64 + d) * (size_t)T + r], w1, acc);
            if (nch > 2) acc = fmaf(Opart[((h * 4 + 2) * 64 + d) * (size_t)T + r], w2, acc);
            if (nch > 3) acc = fmaf(Opart[((h * 4 + 3) * 64 + d) * (size_t)T + r], w3, acc);
            const unsigned short hv = f2bf(acc);
            ((unsigned short*)&hh)[j] = hv;
            ((unsigned short*)&ll)[j] = f2bf(acc - bf2f(hv));
        }
        *(ushort4*)&AOH[(size_t)r * QDIM + h * 64 + d4 * 4] = hh;
        *(ushort4*)&AOL[(size_t)r * QDIM + h * 64 + d4 * 4] = ll;
    }
}

// --------------------------------------------- O-proj MFMA + bias + residual
// out[c][t]: M = c, N = t, K = o(896). A = OW[c][o], B = AO[t][o].
#define PSA_H 0
#define PSA_L 8192
#define PSW_H 16384
#define PSW_L 24576

__global__ __launch_bounds__(256) void oproj_mfma_kernel(
    const unsigned short* __restrict__ AOH, const unsigned short* __restrict__ AOL,
    const unsigned short* __restrict__ OWH, const unsigned short* __restrict__ OWL,
    const float* __restrict__ o_b, const float* __restrict__ x,
    float* __restrict__ out)
{
    const int t0 = blockIdx.x * 64;
    const int c0 = blockIdx.y * 64;
    const int tid = threadIdx.x;
    const int wave = tid >> 6, lane = tid & 63;
    const int lg = lane >> 4, lq = lane & 15;
    const int wr = wave >> 1, wc = wave & 1;

    __shared__ __align__(16) unsigned char sm[32768];

    float4v acc[2][2];
    acc[0][0] = (float4v)0.f; acc[0][1] = (float4v)0.f;
    acc[1][0] = (float4v)0.f; acc[1][1] = (float4v)0.f;

    for (int k0 = 0; k0 < QDIM; k0 += 64) {
        __syncthreads();
        #pragma unroll
        for (int rep = 0; rep < 2; ++rep) {
            const int ci = tid + rep * 256;
            const int row = ci >> 3, cc = ci & 7;
            const int dst = row * 128 + ((cc * 16) ^ ((row & 7) << 4));
            *(uint4*)(sm + PSA_H + dst) = *(const uint4*)&AOH[(size_t)(t0 + row) * QDIM + k0 + cc * 8];
            *(uint4*)(sm + PSA_L + dst) = *(const uint4*)&AOL[(size_t)(t0 + row) * QDIM + k0 + cc * 8];
            *(uint4*)(sm + PSW_H + dst) = *(const uint4*)&OWH[(size_t)(c0 + row) * QDIM + k0 + cc * 8];
            *(uint4*)(sm + PSW_L + dst) = *(const uint4*)&OWL[(size_t)(c0 + row) * QDIM + k0 + cc * 8];
        }
        __syncthreads();
        #pragma unroll
        for (int kk = 0; kk < 2; ++kk) {
            short8 ah[2], al[2], bh[2], bl[2];
            #pragma unroll
            for (int nt = 0; nt < 2; ++nt) {
                const int row = wc * 32 + nt * 16 + lq;
                const int col = (kk * 64 + lg * 16) ^ ((row & 7) << 4);
                bh[nt] = *(const short8*)(sm + PSA_H + row * 128 + col);
                bl[nt] = *(const short8*)(sm + PSA_L + row * 128 + col);
            }
            #pragma unroll
            for (int mt = 0; mt < 2; ++mt) {
                const int row = wr * 32 + mt * 16 + lq;
                const int col = (kk * 64 + lg * 16) ^ ((row & 7) << 4);
                ah[mt] = *(const short8*)(sm + PSW_H + row * 128 + col);
                al[mt] = *(const short8*)(sm + PSW_L + row * 128 + col);
            }
            #pragma unroll
            for (int mt = 0; mt < 2; ++mt) {
                #pragma unroll
                for (int nt = 0; nt < 2; ++nt) {
                    acc[mt][nt] = __builtin_amdgcn_mfma_f32_16x16x32_bf16(ah[mt], bh[nt], acc[mt][nt], 0, 0, 0);
                    acc[mt][nt] = __builtin_amdgcn_mfma_f32_16x16x32_bf16(ah[mt], bl[nt], acc[mt][nt], 0, 0, 0);
                    acc[mt][nt] = __builtin_amdgcn_mfma_f32_16x16x32_bf16(al[mt], bh[nt], acc[mt][nt], 0, 0, 0);
                }
            }
        }
    }

    #pragma unroll
    for (int mt = 0; mt < 2; ++mt) {
        const int cb = c0 + wr * 32 + mt * 16 + lg * 4;
        #pragma unroll
        for (int nt = 0; nt < 2; ++nt) {
            const int t = t0 + wc * 32 + nt * 16 + lq;
            #pragma unroll
            for (int j = 0; j < 4; ++j) {
                const int c = cb + j;
                out[(size_t)c * T + t] = acc[mt][nt][j] + o_b[c] + x[(size_t)c * T + t];
            }
        }
    }
}

// ---------------------------------------------------------------- launcher
extern "C" void kernel_launch(void* const* d_in, const int* in_sizes, int n_in,
                              void* d_out, int out_size, void* d_ws, size_t ws_size,
                              hipStream_t stream) {
    const float* x        = (const float*)d_in[0];
    const float* rope_cos = (const float*)d_in[1];
    const float* rope_sin = (const float*)d_in[2];
    const float* norm_w   = (const float*)d_in[4];
    const float* qkv_w    = (const float*)d_in[5];
    const float* qkv_b    = (const float*)d_in[6];
    const float* o_w      = (const float*)d_in[7];
    const float* o_b      = (const float*)d_in[8];
    const float* sinks    = (const float*)d_in[9];
    float* out = (float*)d_out;

    // fp32 region
    float* ws    = (float*)d_ws;
    float* rpart = ws;                       // 20480
    float* rstd  = rpart + 20480;            // 2048
    float* Opart = rstd + 2048;              // 7340032
    float* Mpart = Opart + 7340032;          // 114688
    float* Lpart = Mpart + 114688;           // 114688
    // bf16 region
    unsigned short* bws = (unsigned short*)(Lpart + 114688);
    unsigned short* Qh  = bws;               // 1835008
    unsigned short* Ql  = Qh  + 1835008;
    unsigned short* Kh  = Ql  + 1835008;     // 262144
    unsigned short* Kl  = Kh  + 262144;
    unsigned short* Vth = Kl  + 262144;
    unsigned short* Vtl = Vth + 262144;
    unsigned short* XnH = Vtl + 262144;      // 1310720
    unsigned short* XnL = XnH + 1310720;
    unsigned short* WqH = XnL + 1310720;     // 737280
    unsigned short* WqL = WqH + 737280;
    unsigned short* OWH = WqL + 737280;      // 573440
    unsigned short* OWL = OWH + 573440;
    unsigned short* AOH = OWL + 573440;      // 1835008
    unsigned short* AOL = AOH + 1835008;

    rstd_partial_kernel<<<dim3(8, 10), 256, 0, stream>>>(x, rpart);
    rstd_final_kernel<<<8, 256, 0, stream>>>(rpart, rstd);
    cast_hilo_kernel<<<720, 256, 0, stream>>>(qkv_w, WqH, WqL, QKV_DIM * DM / 4);
    cast_hilo_kernel<<<560, 256, 0, stream>>>(o_w, OWH, OWL, DM * QDIM / 4);
    xnorm_kernel<<<dim3(32, 10), 256, 0, stream>>>(x, norm_w, rstd, XnH, XnL);
    qkv_mfma_kernel<<<dim3(32, 18), 256, 0, stream>>>(
        XnH, XnL, WqH, WqL, qkv_b, rope_cos, rope_sin, Qh, Ql, Kh, Kl, Vth, Vtl);
    attn_mfma_kernel<<<dim3(32, NH, 4), 256, 0, stream>>>(
        Qh, Ql, Kh, Kl, Vth, Vtl, sinks, Opart, Mpart, Lpart);
    attn_combine_kernel<<<NH * T / 256, 256, 0, stream>>>(Opart, Mpart, Lpart, AOH, AOL);
    oproj_mfma_kernel<<<dim3(32, 10), 256, 0, stream>>>(AOH, AOL, OWH, OWL, o_b, x, out);
}

// Round 6
// 250.846 us; speedup vs baseline: 3.9888x; 1.0674x over previous
//
#include <hip/hip_runtime.h>
#include <math.h>

#define T 2048
#define DM 640
#define NH 14
#define NKV 2
#define HPK 7
#define HD 64
#define QDIM 896
#define QKV_DIM 1152

// 64^-0.25 * sqrt(log2(e)): folds base-2 softmax into Q/K scaling
constexpr float QK_SCALE2 = 0.35355339059327373f * 1.2011224087864498f;
constexpr float EPSF = 1e-5f;

typedef __attribute__((ext_vector_type(8))) short short8;   // 8 bf16 = 4 VGPR
typedef __attribute__((ext_vector_type(4))) float float4v;  // MFMA acc
typedef unsigned short ush;

static __device__ __forceinline__ ush f2bf(float f) {
    union { float f; unsigned u; } v; v.f = f;
    unsigned r = v.u + 0x7fffu + ((v.u >> 16) & 1u);
    return (ush)(r >> 16);
}
static __device__ __forceinline__ float bf2f(ush s) {
    union { unsigned u; float f; } v; v.u = ((unsigned)s) << 16;
    return v.f;
}

// ---------------------------------------------------------------- RMSNorm rstd (fused)
__global__ __launch_bounds__(256) void rstd_kernel(
    const float* __restrict__ x, float* __restrict__ rstd)
{
    const int t0 = blockIdx.x * 64;
    const int tl = threadIdx.x & 63, cg = threadIdx.x >> 6;
    __shared__ float red[4][64];
    float ss = 0.f;
    for (int c = cg; c < DM; c += 4) {
        const float v = x[(size_t)c * T + t0 + tl];
        ss = fmaf(v, v, ss);
    }
    red[cg][tl] = ss;
    __syncthreads();
    if (threadIdx.x < 64) {
        const float s = red[0][tl] + red[1][tl] + red[2][tl] + red[3][tl];
        rstd[t0 + tl] = rsqrtf(s * (1.0f / DM) + EPSF);
    }
}

// ------------------------------------------------- both weight casts in one launch
__global__ __launch_bounds__(256) void cast2_kernel(
    const float* __restrict__ a, ush* __restrict__ ah, ush* __restrict__ al, int na4,
    const float* __restrict__ b, ush* __restrict__ bh, ush* __restrict__ bl)
{
    const int i = blockIdx.x * 256 + threadIdx.x;
    const float* src; ush *dh, *dl; int j;
    if (i < na4) { src = a; dh = ah; dl = al; j = i; }
    else         { src = b; dh = bh; dl = bl; j = i - na4; }
    const float4 v = ((const float4*)src)[j];
    ushort4 h, l;
    h.x = f2bf(v.x); l.x = f2bf(v.x - bf2f(h.x));
    h.y = f2bf(v.y); l.y = f2bf(v.y - bf2f(h.y));
    h.z = f2bf(v.z); l.z = f2bf(v.z - bf2f(h.z));
    h.w = f2bf(v.w); l.w = f2bf(v.w - bf2f(h.w));
    ((ushort4*)dh)[j] = h;
    ((ushort4*)dl)[j] = l;
}

// ------------------------------------------------- normed x, transposed to [t][c]
__global__ __launch_bounds__(256) void xnorm_kernel(
    const float* __restrict__ x, const float* __restrict__ norm_w,
    const float* __restrict__ rstd,
    ush* __restrict__ XnH, ush* __restrict__ XnL)
{
    const int tid = threadIdx.x;
    const int t0 = blockIdx.x * 64;
    const int c0 = blockIdx.y * 64;
    __shared__ float xs[64][65];

    #pragma unroll
    for (int it = 0; it < 4; ++it) {
        const int r = (tid >> 4) + it * 16;
        const int cl = (tid & 15) * 4;
        const float4 v = *(const float4*)&x[(size_t)(c0 + r) * T + t0 + cl];
        xs[r][cl + 0] = v.x; xs[r][cl + 1] = v.y;
        xs[r][cl + 2] = v.z; xs[r][cl + 3] = v.w;
    }
    __syncthreads();
    #pragma unroll
    for (int it = 0; it < 4; ++it) {
        const int tr = (tid >> 4) + it * 16;
        const int cl = (tid & 15) * 4;
        const float rs = rstd[t0 + tr];
        ushort4 h, l;
        const float v0 = xs[cl + 0][tr] * norm_w[c0 + cl + 0] * rs;
        const float v1 = xs[cl + 1][tr] * norm_w[c0 + cl + 1] * rs;
        const float v2 = xs[cl + 2][tr] * norm_w[c0 + cl + 2] * rs;
        const float v3 = xs[cl + 3][tr] * norm_w[c0 + cl + 3] * rs;
        h.x = f2bf(v0); l.x = f2bf(v0 - bf2f(h.x));
        h.y = f2bf(v1); l.y = f2bf(v1 - bf2f(h.y));
        h.z = f2bf(v2); l.z = f2bf(v2 - bf2f(h.z));
        h.w = f2bf(v3); l.w = f2bf(v3 - bf2f(h.w));
        *(ushort4*)&XnH[(size_t)(t0 + tr) * DM + c0 + cl] = h;
        *(ushort4*)&XnL[(size_t)(t0 + tr) * DM + c0 + cl] = l;
    }
}

// ------------------------------------------------- QKV MFMA GEMM (+bias+RoPE), dbuf
#define QSX_H 0
#define QSX_L 8192
#define QSW_H 16384
#define QSW_L 24576

__global__ __launch_bounds__(256) void qkv_mfma_kernel(
    const ush* __restrict__ XnH, const ush* __restrict__ XnL,
    const ush* __restrict__ WH, const ush* __restrict__ WL,
    const float* __restrict__ qkv_b, const float* __restrict__ rope_cos,
    const float* __restrict__ rope_sin,
    ush* __restrict__ Qh, ush* __restrict__ Ql,
    ush* __restrict__ Kh, ush* __restrict__ Kl,
    ush* __restrict__ Vth, ush* __restrict__ Vtl)
{
    const int t0 = blockIdx.x * 64;
    const int o0 = blockIdx.y * 64;
    const int tid = threadIdx.x;
    const int wave = tid >> 6, lane = tid & 63;
    const int lg = lane >> 4, lq = lane & 15;
    const int wr = wave >> 1, wc = wave & 1;

    __shared__ __align__(16) unsigned char sm[65536];

    const int srow0 = tid >> 3, srow1 = srow0 + 32, scc = tid & 7;
    const int dst0 = srow0 * 128 + ((scc * 16) ^ ((srow0 & 7) << 4));
    const int dst1 = srow1 * 128 + ((scc * 16) ^ ((srow1 & 7) << 4));

    uint4 xh0, xl0, wh0, wl0, xh1, xl1, wh1, wl1;

#define QLOAD(c_) do { \
    xh0 = *(const uint4*)&XnH[(size_t)(t0 + srow0) * DM + (c_) + scc * 8]; \
    xl0 = *(const uint4*)&XnL[(size_t)(t0 + srow0) * DM + (c_) + scc * 8]; \
    wh0 = *(const uint4*)&WH [(size_t)(o0 + srow0) * DM + (c_) + scc * 8]; \
    wl0 = *(const uint4*)&WL [(size_t)(o0 + srow0) * DM + (c_) + scc * 8]; \
    xh1 = *(const uint4*)&XnH[(size_t)(t0 + srow1) * DM + (c_) + scc * 8]; \
    xl1 = *(const uint4*)&XnL[(size_t)(t0 + srow1) * DM + (c_) + scc * 8]; \
    wh1 = *(const uint4*)&WH [(size_t)(o0 + srow1) * DM + (c_) + scc * 8]; \
    wl1 = *(const uint4*)&WL [(size_t)(o0 + srow1) * DM + (c_) + scc * 8]; \
} while (0)

#define QSTORE(b_) do { \
    *(uint4*)((b_) + QSX_H + dst0) = xh0; \
    *(uint4*)((b_) + QSX_L + dst0) = xl0; \
    *(uint4*)((b_) + QSW_H + dst0) = wh0; \
    *(uint4*)((b_) + QSW_L + dst0) = wl0; \
    *(uint4*)((b_) + QSX_H + dst1) = xh1; \
    *(uint4*)((b_) + QSX_L + dst1) = xl1; \
    *(uint4*)((b_) + QSW_H + dst1) = wh1; \
    *(uint4*)((b_) + QSW_L + dst1) = wl1; \
} while (0)

    float4v acc[2][2];
    acc[0][0] = (float4v)0.f; acc[0][1] = (float4v)0.f;
    acc[1][0] = (float4v)0.f; acc[1][1] = (float4v)0.f;

    QLOAD(0);
    QSTORE(sm);
    int cur = 0;
    for (int s = 0; s < 10; ++s) {
        if (s < 9) QLOAD((s + 1) * 64);
        __syncthreads();
        const unsigned char* smb = sm + cur * 32768;
        #pragma unroll
        for (int kk = 0; kk < 2; ++kk) {
            short8 ah[2], al[2], bh[2], bl[2];
            #pragma unroll
            for (int nt = 0; nt < 2; ++nt) {
                const int row = wc * 32 + nt * 16 + lq;
                const int col = (kk * 64 + lg * 16) ^ ((row & 7) << 4);
                bh[nt] = *(const short8*)(smb + QSX_H + row * 128 + col);
                bl[nt] = *(const short8*)(smb + QSX_L + row * 128 + col);
            }
            #pragma unroll
            for (int mt = 0; mt < 2; ++mt) {
                const int row = wr * 32 + mt * 16 + lq;
                const int col = (kk * 64 + lg * 16) ^ ((row & 7) << 4);
                ah[mt] = *(const short8*)(smb + QSW_H + row * 128 + col);
                al[mt] = *(const short8*)(smb + QSW_L + row * 128 + col);
            }
            #pragma unroll
            for (int mt = 0; mt < 2; ++mt) {
                #pragma unroll
                for (int nt = 0; nt < 2; ++nt) {
                    acc[mt][nt] = __builtin_amdgcn_mfma_f32_16x16x32_bf16(ah[mt], bh[nt], acc[mt][nt], 0, 0, 0);
                    acc[mt][nt] = __builtin_amdgcn_mfma_f32_16x16x32_bf16(ah[mt], bl[nt], acc[mt][nt], 0, 0, 0);
                    acc[mt][nt] = __builtin_amdgcn_mfma_f32_16x16x32_bf16(al[mt], bh[nt], acc[mt][nt], 0, 0, 0);
                }
            }
        }
        if (s < 9) { QSTORE(sm + ((cur ^ 1) * 32768)); cur ^= 1; }
    }
#undef QLOAD
#undef QSTORE

    const int by = blockIdx.y;
    #pragma unroll
    for (int mt = 0; mt < 2; ++mt) {
        const int d0 = wr * 32 + mt * 16 + lg * 4;
        #pragma unroll
        for (int nt = 0; nt < 2; ++nt) {
            const int t = t0 + wc * 32 + nt * 16 + lq;
            if (by < 16) { // Q or K: bias + rope + scale (incl sqrt(log2e))
                const float e0 = acc[mt][nt][0] + qkv_b[o0 + d0 + 0];
                const float d1 = acc[mt][nt][1] + qkv_b[o0 + d0 + 1];
                const float e2 = acc[mt][nt][2] + qkv_b[o0 + d0 + 2];
                const float d3 = acc[mt][nt][3] + qkv_b[o0 + d0 + 3];
                const float c0v = rope_cos[t * 32 + (d0 >> 1)];
                const float s0v = rope_sin[t * 32 + (d0 >> 1)];
                const float c1v = rope_cos[t * 32 + (d0 >> 1) + 1];
                const float s1v = rope_sin[t * 32 + (d0 >> 1) + 1];
                const float r0 = (e0 * c0v - d1 * s0v) * QK_SCALE2;
                const float r1 = (d1 * c0v + e0 * s0v) * QK_SCALE2;
                const float r2 = (e2 * c1v - d3 * s1v) * QK_SCALE2;
                const float r3 = (d3 * c1v + e2 * s1v) * QK_SCALE2;
                ushort4 h, l;
                h.x = f2bf(r0); l.x = f2bf(r0 - bf2f(h.x));
                h.y = f2bf(r1); l.y = f2bf(r1 - bf2f(h.y));
                h.z = f2bf(r2); l.z = f2bf(r2 - bf2f(h.z));
                h.w = f2bf(r3); l.w = f2bf(r3 - bf2f(h.w));
                if (by < 14) {
                    *(ushort4*)&Qh[((size_t)(by * T + t)) * HD + d0] = h;
                    *(ushort4*)&Ql[((size_t)(by * T + t)) * HD + d0] = l;
                } else {
                    const int h2 = by - 14;
                    *(ushort4*)&Kh[((size_t)(h2 * T + t)) * HD + d0] = h;
                    *(ushort4*)&Kl[((size_t)(h2 * T + t)) * HD + d0] = l;
                }
            } else { // V: bias only, store d-major
                const int h2 = by - 16;
                #pragma unroll
                for (int j = 0; j < 4; ++j) {
                    const float val = acc[mt][nt][j] + qkv_b[o0 + d0 + j];
                    const ush hh = f2bf(val);
                    Vth[((size_t)(h2 * HD + d0 + j)) * T + t] = hh;
                    Vtl[((size_t)(h2 * HD + d0 + j)) * T + t] = f2bf(val - bf2f(hh));
                }
            }
        }
    }
}

// --------------------------------------------- attention: MFMA flash, no split-K, dbuf
// sm: 2 x 32KB KV buffers (KH,KL,VH,VL @ 8KB each) + per-wave P buffer (16 rows x 36 u32)
__global__ __launch_bounds__(256) void attn_mfma_kernel(
    const ush* __restrict__ Qh, const ush* __restrict__ Ql,
    const ush* __restrict__ Kh, const ush* __restrict__ Kl,
    const ush* __restrict__ Vth, const ush* __restrict__ Vtl,
    const float* __restrict__ sinks,
    ush* __restrict__ AOH, ush* __restrict__ AOL)
{
    const int qt = 31 - (int)blockIdx.x;   // longest blocks dispatch first
    const int h  = blockIdx.y;
    const int kvh = h / HPK;
    const int tid = threadIdx.x;
    const int wave = tid >> 6, lane = tid & 63;
    const int lg = lane >> 4, lq = lane & 15;
    const int qbase = qt * 64 + wave * 16;
    const int myq = qbase + lq;

    __shared__ __align__(16) unsigned char sm[2 * 32768 + 4 * 2304];
    unsigned int* Pl = (unsigned int*)(sm + 65536) + wave * (16 * 36);

    short8 qf[2][2];
    #pragma unroll
    for (int kk = 0; kk < 2; ++kk) {
        const size_t qoff = ((size_t)(h * T + myq)) * HD + kk * 32 + lg * 8;
        qf[kk][0] = *(const short8*)&Qh[qoff];
        qf[kk][1] = *(const short8*)&Ql[qoff];
    }

    float4v oacc[4];
    #pragma unroll
    for (int dt = 0; dt < 4; ++dt) oacc[dt] = (float4v)0.f;

    float m2 = sinks[h];   // sink logit in base-2 units is exactly sinks[h]
    float l  = 1.0f;

    const ush* Khp = Kh + (size_t)kvh * T * HD;
    const ush* Klp = Kl + (size_t)kvh * T * HD;
    const ush* Vhp = Vth + (size_t)kvh * HD * T;
    const ush* Vlp = Vtl + (size_t)kvh * HD * T;

    const int srow0 = tid >> 3, srow1 = srow0 + 32, scc = tid & 7;
    const int dst0 = srow0 * 128 + ((scc * 16) ^ ((srow0 & 7) << 4));
    const int dst1 = srow1 * 128 + ((scc * 16) ^ ((srow1 & 7) << 4));

    uint4 rk0h, rk0l, rv0h, rv0l, rk1h, rk1l, rv1h, rv1l;

#define ALOAD(kb_) do { \
    rk0h = *(const uint4*)(Khp + (size_t)((kb_) + srow0) * HD + scc * 8); \
    rk0l = *(const uint4*)(Klp + (size_t)((kb_) + srow0) * HD + scc * 8); \
    rv0h = *(const uint4*)(Vhp + (size_t)srow0 * T + (kb_) + scc * 8); \
    rv0l = *(const uint4*)(Vlp + (size_t)srow0 * T + (kb_) + scc * 8); \
    rk1h = *(const uint4*)(Khp + (size_t)((kb_) + srow1) * HD + scc * 8); \
    rk1l = *(const uint4*)(Klp + (size_t)((kb_) + srow1) * HD + scc * 8); \
    rv1h = *(const uint4*)(Vhp + (size_t)srow1 * T + (kb_) + scc * 8); \
    rv1l = *(const uint4*)(Vlp + (size_t)srow1 * T + (kb_) + scc * 8); \
} while (0)

#define ASTORE(b_) do { \
    *(uint4*)((b_) + 0     + dst0) = rk0h; \
    *(uint4*)((b_) + 8192  + dst0) = rk0l; \
    *(uint4*)((b_) + 16384 + dst0) = rv0h; \
    *(uint4*)((b_) + 24576 + dst0) = rv0l; \
    *(uint4*)((b_) + 0     + dst1) = rk1h; \
    *(uint4*)((b_) + 8192  + dst1) = rk1l; \
    *(uint4*)((b_) + 16384 + dst1) = rv1h; \
    *(uint4*)((b_) + 24576 + dst1) = rv1l; \
} while (0)

    ALOAD(0);
    ASTORE(sm);
    int cur = 0;

    for (int kt = 0; kt <= qt; ++kt) {
        const int kb = kt * 64;
        const bool more = (kt < qt);
        if (more) ALOAD(kb + 64);
        __syncthreads();
        unsigned char* smb = sm + cur * 32768;

        // ---- S^T = K . Q^T (3-term hi/lo), scores already in base-2 units
        float4v st[4];
        #pragma unroll
        for (int t = 0; t < 4; ++t) st[t] = (float4v)0.f;
        #pragma unroll
        for (int t = 0; t < 4; ++t) {
            const int row = t * 16 + lq;
            const int rb = row * 128;
            const int sw = (row & 7) << 4;
            #pragma unroll
            for (int kk = 0; kk < 2; ++kk) {
                const int col = (kk * 64 + lg * 16) ^ sw;
                const short8 ah = *(const short8*)(smb + rb + col);
                const short8 al = *(const short8*)(smb + 8192 + rb + col);
                st[t] = __builtin_amdgcn_mfma_f32_16x16x32_bf16(ah, qf[kk][0], st[t], 0, 0, 0);
                st[t] = __builtin_amdgcn_mfma_f32_16x16x32_bf16(ah, qf[kk][1], st[t], 0, 0, 0);
                st[t] = __builtin_amdgcn_mfma_f32_16x16x32_bf16(al, qf[kk][0], st[t], 0, 0, 0);
            }
        }

        // ---- causal mask + online softmax (base-2)
        float pmax = -3e38f;
        #pragma unroll
        for (int t = 0; t < 4; ++t) {
            #pragma unroll
            for (int j = 0; j < 4; ++j) {
                const int key = kb + 16 * t + 4 * lg + j;
                const float s = (key > myq) ? -3e38f : st[t][j];
                st[t][j] = s;
                pmax = fmaxf(pmax, s);
            }
        }
        pmax = fmaxf(pmax, __shfl_xor(pmax, 16));
        pmax = fmaxf(pmax, __shfl_xor(pmax, 32));
        if (__any(pmax > m2)) {
            const float mnew = fmaxf(m2, pmax);
            const float corr = exp2f(m2 - mnew);
            l *= corr;
            #pragma unroll
            for (int dt = 0; dt < 4; ++dt) oacc[dt] *= corr;
            m2 = mnew;
        }
        float psum = 0.f;
        #pragma unroll
        for (int t = 0; t < 4; ++t) {
            #pragma unroll
            for (int j = 0; j < 4; ++j) {
                const float p = exp2f(st[t][j] - m2);
                st[t][j] = p;
                psum += p;
            }
        }
        psum += __shfl_xor(psum, 16);
        psum += __shfl_xor(psum, 32);
        l += psum;

        // ---- P^T fragments via per-wave LDS (in-order DS, no barrier needed)
        #pragma unroll
        for (int t = 0; t < 4; ++t) {
            #pragma unroll
            for (int j2 = 0; j2 < 2; ++j2) {
                const unsigned int u = (unsigned int)f2bf(st[t][2 * j2]) |
                                       ((unsigned int)f2bf(st[t][2 * j2 + 1]) << 16);
                Pl[lq * 36 + t * 8 + lg * 2 + j2] = u;
            }
        }

        // ---- O^T += (V_hi + V_lo) . P^T  (2-term)
        #pragma unroll
        for (int c = 0; c < 2; ++c) {
            const short8 pf = *(const short8*)&Pl[lq * 36 + c * 16 + lg * 4];
            #pragma unroll
            for (int dt = 0; dt < 4; ++dt) {
                const int row = dt * 16 + lq;
                const int rb = row * 128;
                const int col = (c * 64 + lg * 16) ^ ((row & 7) << 4);
                const short8 vh = *(const short8*)(smb + 16384 + rb + col);
                const short8 vl = *(const short8*)(smb + 24576 + rb + col);
                oacc[dt] = __builtin_amdgcn_mfma_f32_16x16x32_bf16(vh, pf, oacc[dt], 0, 0, 0);
                oacc[dt] = __builtin_amdgcn_mfma_f32_16x16x32_bf16(vl, pf, oacc[dt], 0, 0, 0);
            }
        }

        if (more) { ASTORE(sm + ((cur ^ 1) * 32768)); cur ^= 1; }
    }
#undef ALOAD
#undef ASTORE

    // ---- normalize + write AO[t][o] bf16 hi/lo directly
    const float invl = 1.0f / l;
    const int r = qbase + lq;
    const size_t obase = (size_t)r * QDIM + h * 64;
    #pragma unroll
    for (int dt = 0; dt < 4; ++dt) {
        ushort4 hh, ll;
        #pragma unroll
        for (int j = 0; j < 4; ++j) {
            const float val = oacc[dt][j] * invl;
            const ush hv = f2bf(val);
            ((ush*)&hh)[j] = hv;
            ((ush*)&ll)[j] = f2bf(val - bf2f(hv));
        }
        *(ushort4*)&AOH[obase + dt * 16 + lg * 4] = hh;
        *(ushort4*)&AOL[obase + dt * 16 + lg * 4] = ll;
    }
}

// --------------------------------------------- O-proj MFMA + bias + residual, dbuf
#define PSA_H 0
#define PSA_L 8192
#define PSW_H 16384
#define PSW_L 24576

__global__ __launch_bounds__(256) void oproj_mfma_kernel(
    const ush* __restrict__ AOH, const ush* __restrict__ AOL,
    const ush* __restrict__ OWH, const ush* __restrict__ OWL,
    const float* __restrict__ o_b, const float* __restrict__ x,
    float* __restrict__ out)
{
    const int t0 = blockIdx.x * 64;
    const int c0 = blockIdx.y * 64;
    const int tid = threadIdx.x;
    const int wave = tid >> 6, lane = tid & 63;
    const int lg = lane >> 4, lq = lane & 15;
    const int wr = wave >> 1, wc = wave & 1;

    __shared__ __align__(16) unsigned char sm[65536];

    const int srow0 = tid >> 3, srow1 = srow0 + 32, scc = tid & 7;
    const int dst0 = srow0 * 128 + ((scc * 16) ^ ((srow0 & 7) << 4));
    const int dst1 = srow1 * 128 + ((scc * 16) ^ ((srow1 & 7) << 4));

    uint4 xh0, xl0, wh0, wl0, xh1, xl1, wh1, wl1;

#define PLOAD(k_) do { \
    xh0 = *(const uint4*)&AOH[(size_t)(t0 + srow0) * QDIM + (k_) + scc * 8]; \
    xl0 = *(const uint4*)&AOL[(size_t)(t0 + srow0) * QDIM + (k_) + scc * 8]; \
    wh0 = *(const uint4*)&OWH[(size_t)(c0 + srow0) * QDIM + (k_) + scc * 8]; \
    wl0 = *(const uint4*)&OWL[(size_t)(c0 + srow0) * QDIM + (k_) + scc * 8]; \
    xh1 = *(const uint4*)&AOH[(size_t)(t0 + srow1) * QDIM + (k_) + scc * 8]; \
    xl1 = *(const uint4*)&AOL[(size_t)(t0 + srow1) * QDIM + (k_) + scc * 8]; \
    wh1 = *(const uint4*)&OWH[(size_t)(c0 + srow1) * QDIM + (k_) + scc * 8]; \
    wl1 = *(const uint4*)&OWL[(size_t)(c0 + srow1) * QDIM + (k_) + scc * 8]; \
} while (0)

#define PSTORE(b_) do { \
    *(uint4*)((b_) + PSA_H + dst0) = xh0; \
    *(uint4*)((b_) + PSA_L + dst0) = xl0; \
    *(uint4*)((b_) + PSW_H + dst0) = wh0; \
    *(uint4*)((b_) + PSW_L + dst0) = wl0; \
    *(uint4*)((b_) + PSA_H + dst1) = xh1; \
    *(uint4*)((b_) + PSA_L + dst1) = xl1; \
    *(uint4*)((b_) + PSW_H + dst1) = wh1; \
    *(uint4*)((b_) + PSW_L + dst1) = wl1; \
} while (0)

    float4v acc[2][2];
    acc[0][0] = (float4v)0.f; acc[0][1] = (float4v)0.f;
    acc[1][0] = (float4v)0.f; acc[1][1] = (float4v)0.f;

    PLOAD(0);
    PSTORE(sm);
    int cur = 0;
    for (int s = 0; s < 14; ++s) {
        if (s < 13) PLOAD((s + 1) * 64);
        __syncthreads();
        const unsigned char* smb = sm + cur * 32768;
        #pragma unroll
        for (int kk = 0; kk < 2; ++kk) {
            short8 ah[2], al[2], bh[2], bl[2];
            #pragma unroll
            for (int nt = 0; nt < 2; ++nt) {
                const int row = wc * 32 + nt * 16 + lq;
                const int col = (kk * 64 + lg * 16) ^ ((row & 7) << 4);
                bh[nt] = *(const short8*)(smb + PSA_H + row * 128 + col);
                bl[nt] = *(const short8*)(smb + PSA_L + row * 128 + col);
            }
            #pragma unroll
            for (int mt = 0; mt < 2; ++mt) {
                const int row = wr * 32 + mt * 16 + lq;
                const int col = (kk * 64 + lg * 16) ^ ((row & 7) << 4);
                ah[mt] = *(const short8*)(smb + PSW_H + row * 128 + col);
                al[mt] = *(const short8*)(smb + PSW_L + row * 128 + col);
            }
            #pragma unroll
            for (int mt = 0; mt < 2; ++mt) {
                #pragma unroll
                for (int nt = 0; nt < 2; ++nt) {
                    acc[mt][nt] = __builtin_amdgcn_mfma_f32_16x16x32_bf16(ah[mt], bh[nt], acc[mt][nt], 0, 0, 0);
                    acc[mt][nt] = __builtin_amdgcn_mfma_f32_16x16x32_bf16(ah[mt], bl[nt], acc[mt][nt], 0, 0, 0);
                    acc[mt][nt] = __builtin_amdgcn_mfma_f32_16x16x32_bf16(al[mt], bh[nt], acc[mt][nt], 0, 0, 0);
                }
            }
        }
        if (s < 13) { PSTORE(sm + ((cur ^ 1) * 32768)); cur ^= 1; }
    }
#undef PLOAD
#undef PSTORE

    #pragma unroll
    for (int mt = 0; mt < 2; ++mt) {
        const int cb = c0 + wr * 32 + mt * 16 + lg * 4;
        #pragma unroll
        for (int nt = 0; nt < 2; ++nt) {
            const int t = t0 + wc * 32 + nt * 16 + lq;
            #pragma unroll
            for (int j = 0; j < 4; ++j) {
                const int c = cb + j;
                out[(size_t)c * T + t] = acc[mt][nt][j] + o_b[c] + x[(size_t)c * T + t];
            }
        }
    }
}

// ---------------------------------------------------------------- launcher
extern "C" void kernel_launch(void* const* d_in, const int* in_sizes, int n_in,
                              void* d_out, int out_size, void* d_ws, size_t ws_size,
                              hipStream_t stream) {
    const float* x        = (const float*)d_in[0];
    const float* rope_cos = (const float*)d_in[1];
    const float* rope_sin = (const float*)d_in[2];
    const float* norm_w   = (const float*)d_in[4];
    const float* qkv_w    = (const float*)d_in[5];
    const float* qkv_b    = (const float*)d_in[6];
    const float* o_w      = (const float*)d_in[7];
    const float* o_b      = (const float*)d_in[8];
    const float* sinks    = (const float*)d_in[9];
    float* out = (float*)d_out;

    float* ws   = (float*)d_ws;
    float* rstd = ws;                        // 2048
    ush* bws = (ush*)(rstd + 2048);
    ush* Qh  = bws;                          // 1835008
    ush* Ql  = Qh  + 1835008;
    ush* Kh  = Ql  + 1835008;                // 262144
    ush* Kl  = Kh  + 262144;
    ush* Vth = Kl  + 262144;
    ush* Vtl = Vth + 262144;
    ush* XnH = Vtl + 262144;                 // 1310720
    ush* XnL = XnH + 1310720;
    ush* WqH = XnL + 1310720;                // 737280
    ush* WqL = WqH + 737280;
    ush* OWH = WqL + 737280;                 // 573440
    ush* OWL = OWH + 573440;
    ush* AOH = OWL + 573440;                 // 1835008
    ush* AOL = AOH + 1835008;

    rstd_kernel<<<32, 256, 0, stream>>>(x, rstd);
    cast2_kernel<<<1280, 256, 0, stream>>>(qkv_w, WqH, WqL, QKV_DIM * DM / 4,
                                           o_w, OWH, OWL);
    xnorm_kernel<<<dim3(32, 10), 256, 0, stream>>>(x, norm_w, rstd, XnH, XnL);
    qkv_mfma_kernel<<<dim3(32, 18), 256, 0, stream>>>(
        XnH, XnL, WqH, WqL, qkv_b, rope_cos, rope_sin, Qh, Ql, Kh, Kl, Vth, Vtl);
    attn_mfma_kernel<<<dim3(32, NH), 256, 0, stream>>>(
        Qh, Ql, Kh, Kl, Vth, Vtl, sinks, AOH, AOL);
    oproj_mfma_kernel<<<dim3(32, 10), 256, 0, stream>>>(AOH, AOL, OWH, OWL, o_b, x, out);
}